// Round 1
// baseline (2223.586 us; speedup 1.0000x reference)
//
#include <hip/hip_runtime.h>

#define HID 128
#define NREL 8
#define NBASIS 4

// ---------------------------------------------------------------- CSR build
__global__ void hist_kernel(const int* __restrict__ ei, const int* __restrict__ et,
                            int* __restrict__ cnt, int E) {
  int i = blockIdx.x * blockDim.x + threadIdx.x;
  int stride = gridDim.x * blockDim.x;
  for (int e = i; e < E; e += stride) {
    int dst = ei[E + e];
    int r = et[e];
    atomicAdd(&cnt[dst * NREL + r], 1);
  }
}

__global__ __launch_bounds__(256) void scanA_kernel(const int* __restrict__ cnt,
                                                    int* __restrict__ rowptr,
                                                    int* __restrict__ blocksum, int N) {
  int t = threadIdx.x;
  int n = blockIdx.x * 256 + t;
  int deg = 0;
  if (n < N) {
#pragma unroll
    for (int r = 0; r < NREL; ++r) deg += cnt[n * NREL + r];
  }
  __shared__ int s[256];
  s[t] = deg;
  __syncthreads();
  for (int off = 1; off < 256; off <<= 1) {
    int v = (t >= off) ? s[t - off] : 0;
    __syncthreads();
    s[t] += v;
    __syncthreads();
  }
  if (n < N) rowptr[n + 1] = s[t];
  if (t == 255) blocksum[blockIdx.x] = s[255];
}

__global__ __launch_bounds__(1024) void scanB_kernel(const int* __restrict__ bs,
                                                     int* __restrict__ bo, int nb) {
  int t = threadIdx.x;
  __shared__ int s[1024];
  int v = (t < nb) ? bs[t] : 0;
  s[t] = v;
  __syncthreads();
  for (int off = 1; off < 1024; off <<= 1) {
    int u = (t >= off) ? s[t - off] : 0;
    __syncthreads();
    s[t] += u;
    __syncthreads();
  }
  if (t < nb) bo[t] = s[t] - v;  // exclusive block offset
}

__global__ __launch_bounds__(256) void scanC_kernel(int* __restrict__ rowptr,
                                                    const int* __restrict__ bo,
                                                    int* __restrict__ cursor, int N) {
  int n = blockIdx.x * 256 + threadIdx.x;
  if (n < N) {
    int v = rowptr[n + 1] + bo[blockIdx.x];
    rowptr[n + 1] = v;
    if (n + 1 < N) cursor[n + 1] = v;
    if (n == 0) { rowptr[0] = 0; cursor[0] = 0; }
  }
}

__global__ void scatter_kernel(const int* __restrict__ ei, const int* __restrict__ et,
                               int* __restrict__ cursor, int* __restrict__ csr, int E) {
  int i = blockIdx.x * blockDim.x + threadIdx.x;
  int stride = gridDim.x * blockDim.x;
  for (int e = i; e < E; e += stride) {
    int dst = ei[E + e];
    int src = ei[e];
    int r = et[e];
    int pos = atomicAdd(&cursor[dst], 1);
    csr[pos] = src | (r << 28);  // src < 2^28, r < 8
  }
}

// ------------------------------------------------ per-node basis aggregation
// aggB[n_local, b*128+i] = sum_e (comp[r_e,b]/max(cnt[n,r_e],1)) * h[src_e, i]
__global__ __launch_bounds__(128) void agg_kernel(
    const float* __restrict__ h, const int* __restrict__ rowptr,
    const int* __restrict__ csr, const int* __restrict__ cnt,
    const float* __restrict__ comp, float* __restrict__ aggB, int row0) {
  int n = row0 + blockIdx.x;
  int i = threadIdx.x;
  float4 w[NREL];
#pragma unroll
  for (int r = 0; r < NREL; ++r) {
    float inv = 1.0f / fmaxf((float)cnt[n * NREL + r], 1.0f);
    w[r] = make_float4(comp[r * NBASIS + 0] * inv, comp[r * NBASIS + 1] * inv,
                       comp[r * NBASIS + 2] * inv, comp[r * NBASIS + 3] * inv);
  }
  float a0 = 0.f, a1 = 0.f, a2 = 0.f, a3 = 0.f;
  int e0 = rowptr[n], e1 = rowptr[n + 1];
  for (int j = e0; j < e1; ++j) {
    int p = csr[j];
    int s = p & 0x0FFFFFFF;
    int r = ((unsigned)p) >> 28;
    float v = h[(size_t)s * HID + i];
    float4 ww = w[r];
    a0 = fmaf(ww.x, v, a0);
    a1 = fmaf(ww.y, v, a1);
    a2 = fmaf(ww.z, v, a2);
    a3 = fmaf(ww.w, v, a3);
  }
  float* o = aggB + (size_t)blockIdx.x * (NBASIS * HID) + i;
  o[0] = a0;
  o[HID] = a1;
  o[2 * HID] = a2;
  o[3 * HID] = a3;
}

// ------------------------------------------------------------- fused GEMM
// C[m, 0..BN) = A1[m,:k1] @ B1 + A2[m,:k2] @ B2 + bias  (optional relu)
// k1, k2 multiples of 64 (k2 may be 0). B row-major [k][BN].
template <int BN>
__global__ __launch_bounds__(256) void gemm_kernel(
    const float* __restrict__ A1, int k1, const float* __restrict__ B1,
    const float* __restrict__ A2, int k2, const float* __restrict__ B2,
    const float* __restrict__ bias, float* __restrict__ C, int rows, int relu) {
  constexpr int BM = 64, BK = 64;
  constexpr int TC = BN / 16;
  __shared__ float As[BM][BK + 4];  // +4 pad keeps float4 alignment, spreads banks
  __shared__ float Bs[BK][BN];
  const int t = threadIdx.x;
  const int tx = t & 15, ty = t >> 4;
  const int m0 = blockIdx.x * BM;
  float acc[4][TC];
#pragma unroll
  for (int j = 0; j < 4; ++j)
#pragma unroll
    for (int c = 0; c < TC; ++c) acc[j][c] = 0.f;
  const int nk1 = k1 >> 6, nk2 = k2 >> 6;
  const int nk = nk1 + nk2;
  for (int kc = 0; kc < nk; ++kc) {
    const float* Asrc;
    const float* Bsrc;
    int lda, kbase;
    if (kc < nk1) {
      Asrc = A1; lda = k1; kbase = kc << 6; Bsrc = B1 + (size_t)kbase * BN;
    } else {
      Asrc = A2; lda = k2; kbase = (kc - nk1) << 6; Bsrc = B2 + (size_t)kbase * BN;
    }
    // stage A tile 64x64
#pragma unroll
    for (int l = 0; l < 4; ++l) {
      int idx = (t + l * 256) * 4;
      int row = idx >> 6, kk = idx & 63;
      float4 v = make_float4(0.f, 0.f, 0.f, 0.f);
      int grow = m0 + row;
      if (grow < rows)
        v = *reinterpret_cast<const float4*>(Asrc + (size_t)grow * lda + kbase + kk);
      *reinterpret_cast<float4*>(&As[row][kk]) = v;
    }
    // stage B tile 64xBN
    constexpr int BL = (BK * BN) / 1024;
#pragma unroll
    for (int l = 0; l < BL; ++l) {
      int idx = (t + l * 256) * 4;
      int row = idx / BN, col = idx % BN;
      float4 v = *reinterpret_cast<const float4*>(Bsrc + (size_t)row * BN + col);
      *reinterpret_cast<float4*>(&Bs[row][col]) = v;
    }
    __syncthreads();
#pragma unroll 8
    for (int kk = 0; kk < BK; ++kk) {
      float a[4], b[TC];
#pragma unroll
      for (int j = 0; j < 4; ++j) a[j] = As[ty * 4 + j][kk];
#pragma unroll
      for (int c = 0; c < TC; ++c) b[c] = Bs[kk][tx * TC + c];
#pragma unroll
      for (int j = 0; j < 4; ++j)
#pragma unroll
        for (int c = 0; c < TC; ++c) acc[j][c] = fmaf(a[j], b[c], acc[j][c]);
    }
    __syncthreads();
  }
#pragma unroll
  for (int j = 0; j < 4; ++j) {
    int grow = m0 + ty * 4 + j;
    if (grow < rows) {
#pragma unroll
      for (int c = 0; c < TC; ++c) {
        int col = tx * TC + c;
        float v = acc[j][c] + bias[col];
        if (relu) v = fmaxf(v, 0.f);
        C[(size_t)grow * BN + col] = v;
      }
    }
  }
}

// ------------------------------------------------------------- PairNorm
__global__ __launch_bounds__(256) void stats_kernel(const float* __restrict__ x, int N,
                                                    int F, int logF,
                                                    double* __restrict__ colsum,
                                                    double* __restrict__ sumsq) {
  int t = threadIdx.x;
  int col = t & (F - 1);
  int g = t >> logF;
  int G = 256 >> logF;
  float cs = 0.f, ss = 0.f;
  for (int row = blockIdx.x * G + g; row < N; row += gridDim.x * G) {
    float v = x[(size_t)row * F + col];
    cs += v;
    ss = fmaf(v, v, ss);
  }
  __shared__ float scs[256], sss[256];
  scs[t] = cs;
  sss[t] = ss;
  __syncthreads();
  if (t < F) {
    float s = 0.f;
    for (int gg = 0; gg < G; ++gg) s += scs[gg * F + t];
    atomicAdd(&colsum[t], (double)s);
  }
  for (int off = 128; off > 0; off >>= 1) {
    if (t < off) sss[t] += sss[t + off];
    __syncthreads();
  }
  if (t == 0) atomicAdd(sumsq, (double)sss[0]);
}

__global__ __launch_bounds__(128) void finalize_kernel(const double* __restrict__ colsum,
                                                       const double* __restrict__ sumsq,
                                                       int N, int F, float* __restrict__ mu,
                                                       float* __restrict__ scale) {
  int t = threadIdx.x;
  __shared__ double sm[128];
  double m = 0.0;
  if (t < F) {
    m = colsum[t] / (double)N;
    mu[t] = (float)m;
  }
  sm[t] = m * m;
  __syncthreads();
  for (int off = 64; off > 0; off >>= 1) {
    if (t < off) sm[t] += sm[t + off];
    __syncthreads();
  }
  if (t == 0) {
    double var = (sumsq[0] - (double)N * sm[0]) / (double)N;
    scale[0] = (float)(1.0 / sqrt(1e-5 + var));
  }
}

__global__ void apply_kernel(float* __restrict__ x, const float* __restrict__ mu,
                             const float* __restrict__ scale, int total4, int F) {
  int i = blockIdx.x * blockDim.x + threadIdx.x;
  int stride = gridDim.x * blockDim.x;
  float s = scale[0];
  float4* xv = reinterpret_cast<float4*>(x);
  const float4* muv = reinterpret_cast<const float4*>(mu);
  int nmu = F >> 2;
  for (int idx = i; idx < total4; idx += stride) {
    float4 v = xv[idx];
    float4 m = muv[idx & (nmu - 1)];
    v.x = (v.x - m.x) * s;
    v.y = (v.y - m.y) * s;
    v.z = (v.z - m.z) * s;
    v.w = (v.w - m.w) * s;
    xv[idx] = v;
  }
}

// ---------------------------------------------------------------- launcher
extern "C" void kernel_launch(void* const* d_in, const int* in_sizes, int n_in,
                              void* d_out, int out_size, void* d_ws, size_t ws_size,
                              hipStream_t stream) {
  const float* xin    = (const float*)d_in[0];
  const float* W_proj = (const float*)d_in[1];
  const float* b_proj = (const float*)d_in[2];
  const float* basis1 = (const float*)d_in[3];
  const float* comp1  = (const float*)d_in[4];
  const float* root1  = (const float*)d_in[5];
  const float* bias1  = (const float*)d_in[6];
  const float* basis2 = (const float*)d_in[7];
  const float* comp2  = (const float*)d_in[8];
  const float* root2  = (const float*)d_in[9];
  const float* bias2  = (const float*)d_in[10];
  const int*   ei     = (const int*)d_in[11];
  const int*   et     = (const int*)d_in[12];

  const int N  = in_sizes[0] / HID;   // 100000
  const int E  = in_sizes[12];        // 1600000
  const int F2 = in_sizes[10];        // 64

  float* outp = (float*)d_out;                 // [N, F2]   final pairnorm output
  float* h0   = outp + (size_t)N * F2;         // [N, 128]
  float* h1   = h0 + (size_t)N * HID;          // [N, 128]

  char* ws = (char*)d_ws;
  size_t off = 0;
  auto alloc = [&](size_t bytes) -> void* {
    void* p = ws + off;
    off = (off + bytes + 255) & ~(size_t)255;
    return p;
  };
  int*    cnt      = (int*)alloc((size_t)N * NREL * 4);
  int*    rowptr   = (int*)alloc(((size_t)N + 1) * 4);
  int*    cursor   = (int*)alloc((size_t)N * 4);
  int*    csr      = (int*)alloc((size_t)E * 4);
  int*    blocksum = (int*)alloc(1024 * 4);
  int*    blockoff = (int*)alloc(1024 * 4);
  double* stats    = (double*)alloc(129 * 8);  // colsum[128] + sumsq
  float*  mu       = (float*)alloc(128 * 4);
  float*  scale    = (float*)alloc(4);
  float*  aggB     = (float*)(ws + off);
  size_t avail = (ws_size > off) ? ws_size - off : 0;
  size_t rowBytes = (size_t)(NBASIS * HID) * 4;
  long chunk_rows = N;
  if (avail < (size_t)N * rowBytes) chunk_rows = (long)(avail / rowBytes);
  if (chunk_rows < 64) chunk_rows = 64;

  // 1. h0 = relu(x @ W_proj + b_proj)
  gemm_kernel<HID><<<(N + 63) / 64, 256, 0, stream>>>(xin, HID, W_proj, nullptr, 0,
                                                      nullptr, b_proj, h0, N, 1);

  // 2. CSR build (shared by both layers)
  hipMemsetAsync(cnt, 0, (size_t)N * NREL * 4, stream);
  hist_kernel<<<2048, 256, 0, stream>>>(ei, et, cnt, E);
  int nb = (N + 255) / 256;
  scanA_kernel<<<nb, 256, 0, stream>>>(cnt, rowptr, blocksum, N);
  scanB_kernel<<<1, 1024, 0, stream>>>(blocksum, blockoff, nb);
  scanC_kernel<<<nb, 256, 0, stream>>>(rowptr, blockoff, cursor, N);
  scatter_kernel<<<2048, 256, 0, stream>>>(ei, et, cursor, csr, E);

  // 3. layer 1: RGCN -> relu (into h1 slot), then pairnorm in place
  for (long r0 = 0; r0 < N; r0 += chunk_rows) {
    long rows = (N - r0 < chunk_rows) ? (N - r0) : chunk_rows;
    agg_kernel<<<(int)rows, 128, 0, stream>>>(h0, rowptr, csr, cnt, comp1, aggB, (int)r0);
    gemm_kernel<HID><<<(int)((rows + 63) / 64), 256, 0, stream>>>(
        aggB, NBASIS * HID, basis1, h0 + r0 * HID, HID, root1, bias1, h1 + r0 * HID,
        (int)rows, 1);
  }
  hipMemsetAsync(stats, 0, 129 * 8, stream);
  stats_kernel<<<512, 256, 0, stream>>>(h1, N, HID, 7, stats, stats + 128);
  finalize_kernel<<<1, 128, 0, stream>>>(stats, stats + 128, N, HID, mu, scale);
  apply_kernel<<<2048, 256, 0, stream>>>(h1, mu, scale, N * HID / 4, HID);

  // 4. layer 2: RGCN (into out slot), then pairnorm in place
  for (long r0 = 0; r0 < N; r0 += chunk_rows) {
    long rows = (N - r0 < chunk_rows) ? (N - r0) : chunk_rows;
    agg_kernel<<<(int)rows, 128, 0, stream>>>(h1, rowptr, csr, cnt, comp2, aggB, (int)r0);
    gemm_kernel<64><<<(int)((rows + 63) / 64), 256, 0, stream>>>(
        aggB, NBASIS * HID, basis2, h1 + r0 * HID, HID, root2, bias2, outp + r0 * F2,
        (int)rows, 0);
  }
  hipMemsetAsync(stats, 0, 129 * 8, stream);
  stats_kernel<<<512, 256, 0, stream>>>(outp, N, F2, 6, stats, stats + 128);
  finalize_kernel<<<1, 128, 0, stream>>>(stats, stats + 128, N, F2, mu, scale);
  apply_kernel<<<2048, 256, 0, stream>>>(outp, mu, scale, N * F2 / 4, F2);
}

// Round 5
// 1256.788 us; speedup vs baseline: 1.7693x; 1.7693x over previous
//
#include <hip/hip_runtime.h>

#define HID 128
#define NREL 8
#define NBASIS 4

__device__ __forceinline__ float bf2f(unsigned short u) {
  return __uint_as_float(((unsigned int)u) << 16);
}
__device__ __forceinline__ unsigned short f2bf(float f) {
  unsigned int u = __float_as_uint(f);
  u += 0x7fffu + ((u >> 16) & 1u);
  return (unsigned short)(u >> 16);
}

// ---------------------------------------------------------------- CSR build
__global__ void hist_kernel(const int* __restrict__ ei, const int* __restrict__ et,
                            int* __restrict__ cnt, int E) {
  int i = blockIdx.x * blockDim.x + threadIdx.x;
  int stride = gridDim.x * blockDim.x;
  for (int e = i; e < E; e += stride) {
    int dst = ei[E + e];
    int r = et[e];
    atomicAdd(&cnt[dst * NREL + r], 1);
  }
}

__global__ __launch_bounds__(256) void scanA_kernel(const int* __restrict__ cnt,
                                                    int* __restrict__ rowptr,
                                                    int* __restrict__ blocksum, int N) {
  int t = threadIdx.x;
  int n = blockIdx.x * 256 + t;
  int deg = 0;
  if (n < N) {
#pragma unroll
    for (int r = 0; r < NREL; ++r) deg += cnt[n * NREL + r];
  }
  __shared__ int s[256];
  s[t] = deg;
  __syncthreads();
  for (int off = 1; off < 256; off <<= 1) {
    int v = (t >= off) ? s[t - off] : 0;
    __syncthreads();
    s[t] += v;
    __syncthreads();
  }
  if (n < N) rowptr[n + 1] = s[t];
  if (t == 255) blocksum[blockIdx.x] = s[255];
}

__global__ __launch_bounds__(1024) void scanB_kernel(const int* __restrict__ bs,
                                                     int* __restrict__ bo, int nb) {
  int t = threadIdx.x;
  __shared__ int s[1024];
  int v = (t < nb) ? bs[t] : 0;
  s[t] = v;
  __syncthreads();
  for (int off = 1; off < 1024; off <<= 1) {
    int u = (t >= off) ? s[t - off] : 0;
    __syncthreads();
    s[t] += u;
    __syncthreads();
  }
  if (t < nb) bo[t] = s[t] - v;  // exclusive block offset
}

__global__ __launch_bounds__(256) void scanC_kernel(int* __restrict__ rowptr,
                                                    const int* __restrict__ bo,
                                                    int* __restrict__ cursor, int N) {
  int n = blockIdx.x * 256 + threadIdx.x;
  if (n < N) {
    int v = rowptr[n + 1] + bo[blockIdx.x];
    rowptr[n + 1] = v;
    if (n + 1 < N) cursor[n + 1] = v;
    if (n == 0) { rowptr[0] = 0; cursor[0] = 0; }
  }
}

__global__ void scatter_kernel(const int* __restrict__ ei, const int* __restrict__ et,
                               int* __restrict__ cursor, int* __restrict__ csr, int E) {
  int i = blockIdx.x * blockDim.x + threadIdx.x;
  int stride = gridDim.x * blockDim.x;
  for (int e = i; e < E; e += stride) {
    int dst = ei[E + e];
    int src = ei[e];
    int r = et[e];
    int pos = atomicAdd(&cursor[dst], 1);
    csr[pos] = src | (r << 28);  // src < 2^28, r < 8
  }
}

// ------------------------------------------------ per-node basis aggregation
// One wave per node; lane owns 2 feature columns. Gathers bf16 h rows.
// aggB[n_local][b*128+col] (fp32) = sum_e (comp[r_e,b]/max(cnt[n,r_e],1))*h[src_e,col]
__global__ __launch_bounds__(256) void agg_kernel(
    const unsigned short* __restrict__ hb, const int* __restrict__ rowptr,
    const int* __restrict__ csr, const int* __restrict__ cnt,
    const float* __restrict__ comp, float* __restrict__ aggB, int row0, int nrows) {
  __shared__ float4 s_w[4][NREL];  // per-node scaled comp (LDS, not scratch!)
  const int wave = threadIdx.x >> 6;
  const int lane = threadIdx.x & 63;
  const int nl = blockIdx.x * 4 + wave;
  const bool active = nl < nrows;
  const int n = row0 + nl;
  if (active && lane < NREL) {
    int r = lane;
    float inv = 1.0f / fmaxf((float)cnt[(size_t)n * NREL + r], 1.0f);
    s_w[wave][r] = make_float4(comp[r * NBASIS + 0] * inv, comp[r * NBASIS + 1] * inv,
                               comp[r * NBASIS + 2] * inv, comp[r * NBASIS + 3] * inv);
  }
  __syncthreads();
  if (!active) return;
  float a00 = 0.f, a01 = 0.f, a10 = 0.f, a11 = 0.f;
  float a20 = 0.f, a21 = 0.f, a30 = 0.f, a31 = 0.f;
  const int e0 = rowptr[n], e1 = rowptr[n + 1];
  int p = (e0 < e1) ? csr[e0] : 0;
  for (int j = e0; j < e1; ++j) {
    int pn = (j + 1 < e1) ? csr[j + 1] : 0;  // prefetch next edge record
    int s = p & 0x0FFFFFFF;
    int r = ((unsigned int)p) >> 28;
    unsigned int hv =
        *reinterpret_cast<const unsigned int*>(hb + (size_t)s * HID + lane * 2);
    float4 ww = s_w[wave][r];
    float lo = bf2f((unsigned short)(hv & 0xffffu));
    float hi = bf2f((unsigned short)(hv >> 16));
    a00 = fmaf(ww.x, lo, a00); a01 = fmaf(ww.x, hi, a01);
    a10 = fmaf(ww.y, lo, a10); a11 = fmaf(ww.y, hi, a11);
    a20 = fmaf(ww.z, lo, a20); a21 = fmaf(ww.z, hi, a21);
    a30 = fmaf(ww.w, lo, a30); a31 = fmaf(ww.w, hi, a31);
    p = pn;
  }
  float* o = aggB + (size_t)nl * (NBASIS * HID) + lane * 2;
  *reinterpret_cast<float2*>(o + 0 * HID) = make_float2(a00, a01);
  *reinterpret_cast<float2*>(o + 1 * HID) = make_float2(a10, a11);
  *reinterpret_cast<float2*>(o + 2 * HID) = make_float2(a20, a21);
  *reinterpret_cast<float2*>(o + 3 * HID) = make_float2(a30, a31);
}

// ------------------------------------------------------------- fused GEMM
// C[m,:BN] = A1[m,:k1]@B1 + A2[m,:k2]@B2 + bias  (opt relu, opt bf16 copy Cb)
// k1,k2 multiples of 64 (either may be 0). B row-major [k][BN]. A fp32.
template <int BN>
__global__ __launch_bounds__(256) void gemm_kernel(
    const float* __restrict__ A1, int k1, const float* __restrict__ B1,
    const float* __restrict__ A2, int k2, const float* __restrict__ B2,
    const float* __restrict__ bias, float* __restrict__ C,
    unsigned int* __restrict__ Cb, int rows, int relu) {
  constexpr int BM = 64, BK = 64;
  constexpr int TC = BN / 16;
  __shared__ float AsT[BK][BM + 4];  // transposed: one ds_read_b128 per a-frag
  __shared__ float Bs[BK][BN];
  const int t = threadIdx.x;
  const int tx = t & 15, ty = t >> 4;
  const int m0 = blockIdx.x * BM;
  float acc[4][TC];
#pragma unroll
  for (int j = 0; j < 4; ++j)
#pragma unroll
    for (int c = 0; c < TC; ++c) acc[j][c] = 0.f;
  const int nk1 = k1 >> 6, nk2 = k2 >> 6;
  const int nk = nk1 + nk2;
  for (int kc = 0; kc < nk; ++kc) {
    const float* Asrc;
    const float* Bsrc;
    int lda, kbase;
    if (kc < nk1) {
      Asrc = A1; lda = k1; kbase = kc << 6; Bsrc = B1 + (size_t)kbase * BN;
    } else {
      Asrc = A2; lda = k2; kbase = (kc - nk1) << 6; Bsrc = B2 + (size_t)kbase * BN;
    }
#pragma unroll
    for (int l = 0; l < 4; ++l) {
      int idx = (t + l * 256) * 4;
      int row = idx >> 6, kk = idx & 63;
      int grow = m0 + row;
      float4 v = make_float4(0.f, 0.f, 0.f, 0.f);
      if (grow < rows)
        v = *reinterpret_cast<const float4*>(Asrc + (size_t)grow * lda + kbase + kk);
      AsT[kk + 0][row] = v.x;
      AsT[kk + 1][row] = v.y;
      AsT[kk + 2][row] = v.z;
      AsT[kk + 3][row] = v.w;
    }
    constexpr int BL = (BK * BN) / 1024;
#pragma unroll
    for (int l = 0; l < BL; ++l) {
      int idx = (t + l * 256) * 4;
      int row = idx / BN, col = idx % BN;
      *reinterpret_cast<float4*>(&Bs[row][col]) =
          *reinterpret_cast<const float4*>(Bsrc + (size_t)row * BN + col);
    }
    __syncthreads();
#pragma unroll 8
    for (int kk = 0; kk < BK; ++kk) {
      float4 av = *reinterpret_cast<const float4*>(&AsT[kk][ty * 4]);
      float a0 = av.x, a1 = av.y, a2 = av.z, a3 = av.w;
      float b[TC];
#pragma unroll
      for (int c = 0; c < TC; ++c) b[c] = Bs[kk][tx * TC + c];
#pragma unroll
      for (int c = 0; c < TC; ++c) {
        acc[0][c] = fmaf(a0, b[c], acc[0][c]);
        acc[1][c] = fmaf(a1, b[c], acc[1][c]);
        acc[2][c] = fmaf(a2, b[c], acc[2][c]);
        acc[3][c] = fmaf(a3, b[c], acc[3][c]);
      }
    }
    __syncthreads();
  }
#pragma unroll
  for (int j = 0; j < 4; ++j) {
    int grow = m0 + ty * 4 + j;
    if (grow < rows) {
      float vv[TC];
#pragma unroll
      for (int c = 0; c < TC; ++c) {
        float v = acc[j][c] + bias[tx * TC + c];
        if (relu) v = fmaxf(v, 0.f);
        vv[c] = v;
      }
#pragma unroll
      for (int c4 = 0; c4 < TC; c4 += 4)
        *reinterpret_cast<float4*>(&C[(size_t)grow * BN + tx * TC + c4]) =
            make_float4(vv[c4], vv[c4 + 1], vv[c4 + 2], vv[c4 + 3]);
      if (Cb) {
#pragma unroll
        for (int c = 0; c < TC; c += 2)
          Cb[((size_t)grow * BN + tx * TC + c) >> 1] =
              (unsigned int)f2bf(vv[c]) | ((unsigned int)f2bf(vv[c + 1]) << 16);
      }
    }
  }
}

// ------------------------------------------------------------- PairNorm
__global__ __launch_bounds__(256) void stats_kernel(const float* __restrict__ x, int N,
                                                    int F, int logF,
                                                    double* __restrict__ colsum,
                                                    double* __restrict__ sumsq) {
  int t = threadIdx.x;
  int col = t & (F - 1);
  int g = t >> logF;
  int G = 256 >> logF;
  float cs = 0.f, ss = 0.f;
  for (int row = blockIdx.x * G + g; row < N; row += gridDim.x * G) {
    float v = x[(size_t)row * F + col];
    cs += v;
    ss = fmaf(v, v, ss);
  }
  __shared__ float scs[256], sss[256];
  scs[t] = cs;
  sss[t] = ss;
  __syncthreads();
  if (t < F) {
    float s = 0.f;
    for (int gg = 0; gg < G; ++gg) s += scs[gg * F + t];
    atomicAdd(&colsum[t], (double)s);
  }
  for (int off = 128; off > 0; off >>= 1) {
    if (t < off) sss[t] += sss[t + off];
    __syncthreads();
  }
  if (t == 0) atomicAdd(sumsq, (double)sss[0]);
}

__global__ __launch_bounds__(128) void finalize_kernel(const double* __restrict__ colsum,
                                                       const double* __restrict__ sumsq,
                                                       int N, int F, float* __restrict__ mu,
                                                       float* __restrict__ scale) {
  int t = threadIdx.x;
  __shared__ double sm[128];
  double m = 0.0;
  if (t < F) {
    m = colsum[t] / (double)N;
    mu[t] = (float)m;
  }
  sm[t] = m * m;
  __syncthreads();
  for (int off = 64; off > 0; off >>= 1) {
    if (t < off) sm[t] += sm[t + off];
    __syncthreads();
  }
  if (t == 0) {
    double var = (sumsq[0] - (double)N * sm[0]) / (double)N;
    scale[0] = (float)(1.0 / sqrt(1e-5 + var));
  }
}

__global__ void apply_kernel(float* __restrict__ x, const float* __restrict__ mu,
                             const float* __restrict__ scale, int total4, int F,
                             uint2* __restrict__ xb) {
  int i = blockIdx.x * blockDim.x + threadIdx.x;
  int stride = gridDim.x * blockDim.x;
  float s = scale[0];
  float4* xv = reinterpret_cast<float4*>(x);
  const float4* muv = reinterpret_cast<const float4*>(mu);
  int nmu = F >> 2;
  for (int idx = i; idx < total4; idx += stride) {
    float4 v = xv[idx];
    float4 m = muv[idx & (nmu - 1)];
    v.x = (v.x - m.x) * s;
    v.y = (v.y - m.y) * s;
    v.z = (v.z - m.z) * s;
    v.w = (v.w - m.w) * s;
    xv[idx] = v;
    if (xb) {
      uint2 pk;
      pk.x = (unsigned int)f2bf(v.x) | ((unsigned int)f2bf(v.y) << 16);
      pk.y = (unsigned int)f2bf(v.z) | ((unsigned int)f2bf(v.w) << 16);
      xb[idx] = pk;
    }
  }
}

// ---------------------------------------------------------------- launcher
extern "C" void kernel_launch(void* const* d_in, const int* in_sizes, int n_in,
                              void* d_out, int out_size, void* d_ws, size_t ws_size,
                              hipStream_t stream) {
  const float* xin    = (const float*)d_in[0];
  const float* W_proj = (const float*)d_in[1];
  const float* b_proj = (const float*)d_in[2];
  const float* basis1 = (const float*)d_in[3];
  const float* comp1  = (const float*)d_in[4];
  const float* root1  = (const float*)d_in[5];
  const float* bias1  = (const float*)d_in[6];
  const float* basis2 = (const float*)d_in[7];
  const float* comp2  = (const float*)d_in[8];
  const float* root2  = (const float*)d_in[9];
  const float* bias2  = (const float*)d_in[10];
  const int*   ei     = (const int*)d_in[11];
  const int*   et     = (const int*)d_in[12];

  const int N  = in_sizes[0] / HID;   // 100000
  const int E  = in_sizes[12];        // 1600000
  const int F2 = in_sizes[10];        // 64

  float* outp = (float*)d_out;                 // [N, F2]
  float* h0   = outp + (size_t)N * F2;         // [N, 128]
  float* h1   = h0 + (size_t)N * HID;          // [N, 128]

  char* ws = (char*)d_ws;
  size_t off = 0;
  auto alloc = [&](size_t bytes) -> void* {
    void* p = ws + off;
    off = (off + bytes + 255) & ~(size_t)255;
    return p;
  };
  int*    cnt      = (int*)alloc((size_t)N * NREL * 4);
  int*    rowptr   = (int*)alloc(((size_t)N + 1) * 4);
  int*    cursor   = (int*)alloc((size_t)N * 4);
  int*    csr      = (int*)alloc((size_t)E * 4);
  int*    blocksum = (int*)alloc(1024 * 4);
  int*    blockoff = (int*)alloc(1024 * 4);
  double* stats    = (double*)alloc(129 * 8);
  float*  mu       = (float*)alloc(128 * 4);
  float*  scale    = (float*)alloc(4);
  unsigned short* h0b = (unsigned short*)alloc((size_t)N * HID * 2);
  unsigned short* h1b = (unsigned short*)alloc((size_t)N * HID * 2);
  float*  aggB     = (float*)(ws + off);
  size_t avail = (ws_size > off) ? ws_size - off : 0;
  size_t rowBytes = (size_t)(NBASIS * HID) * 4;
  long chunk_rows = N;
  if (avail < (size_t)N * rowBytes) chunk_rows = (long)(avail / rowBytes);
  if (chunk_rows < 64) chunk_rows = 64;

  // 1. h0 = relu(x @ W_proj + b_proj); also write bf16 copy h0b
  gemm_kernel<HID><<<(N + 63) / 64, 256, 0, stream>>>(
      xin, HID, W_proj, nullptr, 0, nullptr, b_proj, h0, (unsigned int*)h0b, N, 1);

  // 2. CSR build (shared by both layers)
  hipMemsetAsync(cnt, 0, (size_t)N * NREL * 4, stream);
  hist_kernel<<<2048, 256, 0, stream>>>(ei, et, cnt, E);
  int nb = (N + 255) / 256;
  scanA_kernel<<<nb, 256, 0, stream>>>(cnt, rowptr, blocksum, N);
  scanB_kernel<<<1, 1024, 0, stream>>>(blocksum, blockoff, nb);
  scanC_kernel<<<nb, 256, 0, stream>>>(rowptr, blockoff, cursor, N);
  scatter_kernel<<<2048, 256, 0, stream>>>(ei, et, cursor, csr, E);

  // 3. layer 1: RGCN -> relu (h1), then pairnorm in place (+ bf16 copy h1b)
  for (long r0 = 0; r0 < N; r0 += chunk_rows) {
    long rows = (N - r0 < chunk_rows) ? (N - r0) : chunk_rows;
    agg_kernel<<<(int)((rows + 3) / 4), 256, 0, stream>>>(h0b, rowptr, csr, cnt, comp1,
                                                          aggB, (int)r0, (int)rows);
    gemm_kernel<HID><<<(int)((rows + 63) / 64), 256, 0, stream>>>(
        aggB, NBASIS * HID, basis1, h0 + r0 * HID, HID, root1, bias1, h1 + r0 * HID,
        nullptr, (int)rows, 1);
  }
  hipMemsetAsync(stats, 0, 129 * 8, stream);
  stats_kernel<<<512, 256, 0, stream>>>(h1, N, HID, 7, stats, stats + 128);
  finalize_kernel<<<1, 128, 0, stream>>>(stats, stats + 128, N, HID, mu, scale);
  apply_kernel<<<2048, 256, 0, stream>>>(h1, mu, scale, N * HID / 4, HID, (uint2*)h1b);

  // 4. layer 2: RGCN (out), then pairnorm in place
  for (long r0 = 0; r0 < N; r0 += chunk_rows) {
    long rows = (N - r0 < chunk_rows) ? (N - r0) : chunk_rows;
    agg_kernel<<<(int)((rows + 3) / 4), 256, 0, stream>>>(h1b, rowptr, csr, cnt, comp2,
                                                          aggB, (int)r0, (int)rows);
    gemm_kernel<64><<<(int)((rows + 63) / 64), 256, 0, stream>>>(
        aggB, NBASIS * HID, basis2, h1 + r0 * HID, HID, root2, bias2, outp + r0 * F2,
        nullptr, (int)rows, 0);
  }
  hipMemsetAsync(stats, 0, 129 * 8, stream);
  stats_kernel<<<512, 256, 0, stream>>>(outp, N, F2, 6, stats, stats + 128);
  finalize_kernel<<<1, 128, 0, stream>>>(stats, stats + 128, N, F2, mu, scale);
  apply_kernel<<<2048, 256, 0, stream>>>(outp, mu, scale, N * F2 / 4, F2, nullptr);
}

// Round 9
// 1028.668 us; speedup vs baseline: 2.1616x; 1.2218x over previous
//
#include <hip/hip_runtime.h>

#define HID 128
#define NREL 8
#define NBASIS 4

typedef __attribute__((ext_vector_type(8))) short bf16x8;
typedef __attribute__((ext_vector_type(4))) float f32x4;

__device__ __forceinline__ float bf2f(unsigned short u) {
  return __uint_as_float(((unsigned int)u) << 16);
}
__device__ __forceinline__ unsigned short f2bf(float f) {
  unsigned int u = __float_as_uint(f);
  u += 0x7fffu + ((u >> 16) & 1u);
  return (unsigned short)(u >> 16);
}
// split fp32x4 into hi/lo bf16 pairs, packed 2-per-u32
__device__ __forceinline__ void split_pack(float4 v, uint2& hp, uint2& lp) {
  unsigned short h0 = f2bf(v.x), h1 = f2bf(v.y), h2 = f2bf(v.z), h3 = f2bf(v.w);
  hp = make_uint2((unsigned)h0 | ((unsigned)h1 << 16),
                  (unsigned)h2 | ((unsigned)h3 << 16));
  unsigned short l0 = f2bf(v.x - bf2f(h0)), l1 = f2bf(v.y - bf2f(h1));
  unsigned short l2 = f2bf(v.z - bf2f(h2)), l3 = f2bf(v.w - bf2f(h3));
  lp = make_uint2((unsigned)l0 | ((unsigned)l1 << 16),
                  (unsigned)l2 | ((unsigned)l3 << 16));
}

// ---------------------------------------------------------------- CSR build
__global__ void hist_kernel(const int* __restrict__ ei, const int* __restrict__ et,
                            int* __restrict__ cnt, int E) {
  int i = blockIdx.x * blockDim.x + threadIdx.x;
  int stride = gridDim.x * blockDim.x;
  for (int e = i; e < E; e += stride) {
    int dst = ei[E + e];
    int r = et[e];
    atomicAdd(&cnt[dst * NREL + r], 1);
  }
}

__global__ __launch_bounds__(256) void scanA_kernel(const int* __restrict__ cnt,
                                                    int* __restrict__ rowptr,
                                                    int* __restrict__ blocksum, int N) {
  int t = threadIdx.x;
  int n = blockIdx.x * 256 + t;
  int deg = 0;
  if (n < N) {
#pragma unroll
    for (int r = 0; r < NREL; ++r) deg += cnt[n * NREL + r];
  }
  __shared__ int s[256];
  s[t] = deg;
  __syncthreads();
  for (int off = 1; off < 256; off <<= 1) {
    int v = (t >= off) ? s[t - off] : 0;
    __syncthreads();
    s[t] += v;
    __syncthreads();
  }
  if (n < N) rowptr[n + 1] = s[t];
  if (t == 255) blocksum[blockIdx.x] = s[255];
}

__global__ __launch_bounds__(1024) void scanB_kernel(const int* __restrict__ bs,
                                                     int* __restrict__ bo, int nb) {
  int t = threadIdx.x;
  __shared__ int s[1024];
  int v = (t < nb) ? bs[t] : 0;
  s[t] = v;
  __syncthreads();
  for (int off = 1; off < 1024; off <<= 1) {
    int u = (t >= off) ? s[t - off] : 0;
    __syncthreads();
    s[t] += u;
    __syncthreads();
  }
  if (t < nb) bo[t] = s[t] - v;  // exclusive block offset
}

__global__ __launch_bounds__(256) void scanC_kernel(int* __restrict__ rowptr,
                                                    const int* __restrict__ bo,
                                                    int* __restrict__ cursor, int N) {
  int n = blockIdx.x * 256 + threadIdx.x;
  if (n < N) {
    int v = rowptr[n + 1] + bo[blockIdx.x];
    rowptr[n + 1] = v;
    if (n + 1 < N) cursor[n + 1] = v;
    if (n == 0) { rowptr[0] = 0; cursor[0] = 0; }
  }
}

__global__ void scatter_kernel(const int* __restrict__ ei, const int* __restrict__ et,
                               int* __restrict__ cursor, int* __restrict__ csr, int E) {
  int i = blockIdx.x * blockDim.x + threadIdx.x;
  int stride = gridDim.x * blockDim.x;
  for (int e = i; e < E; e += stride) {
    int dst = ei[E + e];
    int src = ei[e];
    int r = et[e];
    int pos = atomicAdd(&cursor[dst], 1);
    csr[pos] = src | (r << 28);  // src < 2^28, r < 8
  }
}

// ------------------------------------------------ per-node basis aggregation
__global__ __launch_bounds__(256) void agg_kernel(
    const unsigned short* __restrict__ hb, const int* __restrict__ rowptr,
    const int* __restrict__ csr, const int* __restrict__ cnt,
    const float* __restrict__ comp, float* __restrict__ aggB, int row0, int nrows) {
  __shared__ float4 s_w[4][NREL];  // per-node scaled comp (LDS, not scratch!)
  const int wave = threadIdx.x >> 6;
  const int lane = threadIdx.x & 63;
  const int nl = blockIdx.x * 4 + wave;
  const bool active = nl < nrows;
  const int n = row0 + nl;
  if (active && lane < NREL) {
    int r = lane;
    float inv = 1.0f / fmaxf((float)cnt[(size_t)n * NREL + r], 1.0f);
    s_w[wave][r] = make_float4(comp[r * NBASIS + 0] * inv, comp[r * NBASIS + 1] * inv,
                               comp[r * NBASIS + 2] * inv, comp[r * NBASIS + 3] * inv);
  }
  __syncthreads();
  if (!active) return;
  float a00 = 0.f, a01 = 0.f, a10 = 0.f, a11 = 0.f;
  float a20 = 0.f, a21 = 0.f, a30 = 0.f, a31 = 0.f;
  const int e0 = rowptr[n], e1 = rowptr[n + 1];
  int p = (e0 < e1) ? csr[e0] : 0;
  for (int j = e0; j < e1; ++j) {
    int pn = (j + 1 < e1) ? csr[j + 1] : 0;  // prefetch next edge record
    int s = p & 0x0FFFFFFF;
    int r = ((unsigned int)p) >> 28;
    unsigned int hv =
        *reinterpret_cast<const unsigned int*>(hb + (size_t)s * HID + lane * 2);
    float4 ww = s_w[wave][r];
    float lo = bf2f((unsigned short)(hv & 0xffffu));
    float hi = bf2f((unsigned short)(hv >> 16));
    a00 = fmaf(ww.x, lo, a00); a01 = fmaf(ww.x, hi, a01);
    a10 = fmaf(ww.y, lo, a10); a11 = fmaf(ww.y, hi, a11);
    a20 = fmaf(ww.z, lo, a20); a21 = fmaf(ww.z, hi, a21);
    a30 = fmaf(ww.w, lo, a30); a31 = fmaf(ww.w, hi, a31);
    p = pn;
  }
  float* o = aggB + (size_t)nl * (NBASIS * HID) + lane * 2;
  *reinterpret_cast<float2*>(o + 0 * HID) = make_float2(a00, a01);
  *reinterpret_cast<float2*>(o + 1 * HID) = make_float2(a10, a11);
  *reinterpret_cast<float2*>(o + 2 * HID) = make_float2(a20, a21);
  *reinterpret_cast<float2*>(o + 3 * HID) = make_float2(a30, a31);
}

// ----------------------------------------- weight prep: transpose + bf16 split
// W = concat(Wa [rowsA][N], Wb [K-rowsA][N]); Bt{Hi,Lo}[n][k] = split(W[k][n])
__global__ __launch_bounds__(256) void prep_kernel(
    const float* __restrict__ Wa, int rowsA, const float* __restrict__ Wb, int K,
    int Ncols, unsigned short* __restrict__ BtHi, unsigned short* __restrict__ BtLo) {
  int i = blockIdx.x * 256 + threadIdx.x;
  if (i >= K * Ncols) return;
  int k = i / Ncols, n = i - k * Ncols;
  float w = (k < rowsA) ? Wa[(size_t)k * Ncols + n]
                        : Wb[(size_t)(k - rowsA) * Ncols + n];
  unsigned short h = f2bf(w);
  BtHi[(size_t)n * K + k] = h;
  BtLo[(size_t)n * K + k] = f2bf(w - bf2f(h));
}

// --------------------------------------------------- MFMA GEMM (bf16x3 split)
// C[m,:BN] = (A1[m,:k1] ++ A2[m,:k2]) @ W + bias, W given as Bt{Hi,Lo}[n][k1+k2].
// 64x BN block, 4 waves, BK=32, 16x16x32 bf16 MFMA, fp32 acc.
// A layout: row=lane%16, k=(lane/16)*8+j.  D: col=lane%16, row=4*(lane/16)+reg.
template <int BN>
__global__ __launch_bounds__(256) void mgemm_kernel(
    const float* __restrict__ A1, int k1, const float* __restrict__ A2, int k2,
    const unsigned short* __restrict__ BtHi, const unsigned short* __restrict__ BtLo,
    const float* __restrict__ bias, float* __restrict__ C,
    unsigned short* __restrict__ Cb, int rows, int relu) {
  constexpr int BM = 64, BK = 32;
  constexpr int LDA = BK + 8;  // 40 shorts = 80B pitch: 8-row bank period covers all 32 banks
  constexpr int NF = BN / 64;  // 16-col frags per wave
  __shared__ __align__(16) unsigned short sAh[BM * LDA], sAl[BM * LDA];
  __shared__ __align__(16) unsigned short sBh[BN * LDA], sBl[BN * LDA];
  const int t = threadIdx.x;
  const int wave = t >> 6, lane = t & 63;
  const int fr = lane & 15;        // fragment row (A) / col (B,D)
  const int fk = (lane >> 4) * 8;  // fragment k base
  const int m0 = blockIdx.x * BM;
  const int ldk = k1 + k2;
  const int nk = ldk >> 5, nk1 = k1 >> 5;
  f32x4 acc[4][NF];
#pragma unroll
  for (int i = 0; i < 4; ++i)
#pragma unroll
    for (int j = 0; j < NF; ++j) acc[i][j] = (f32x4){0.f, 0.f, 0.f, 0.f};

  const int arow = t >> 2, aseg = t & 3;  // A staging: row, 8-k segment
  for (int kc = 0; kc < nk; ++kc) {
    {  // stage A: 64x32 fp32 -> split hi/lo bf16
      const float* Asrc; int lda, kb;
      if (kc < nk1) { Asrc = A1; lda = k1; kb = kc << 5; }
      else          { Asrc = A2; lda = k2; kb = (kc - nk1) << 5; }
      float4 v0 = make_float4(0.f, 0.f, 0.f, 0.f), v1 = v0;
      int grow = m0 + arow;
      if (grow < rows) {
        const float* p = Asrc + (size_t)grow * lda + kb + aseg * 8;
        v0 = *reinterpret_cast<const float4*>(p);
        v1 = *reinterpret_cast<const float4*>(p + 4);
      }
      uint2 hp0, lp0, hp1, lp1;
      split_pack(v0, hp0, lp0);
      split_pack(v1, hp1, lp1);
      unsigned short* da = &sAh[arow * LDA + aseg * 8];
      *reinterpret_cast<uint2*>(da) = hp0;
      *reinterpret_cast<uint2*>(da + 4) = hp1;
      unsigned short* dl = &sAl[arow * LDA + aseg * 8];
      *reinterpret_cast<uint2*>(dl) = lp0;
      *reinterpret_cast<uint2*>(dl + 4) = lp1;
    }
    {  // stage B: BN x 32 bf16 hi/lo (pre-transposed in global)
      int k0 = kc << 5;
#pragma unroll
      for (int l = 0; l < (BN * 4) / 256; ++l) {
        int i = t + l * 256;
        int n = i >> 2, seg = i & 3;
        size_t g = (size_t)n * ldk + k0 + seg * 8;
        *reinterpret_cast<uint4*>(&sBh[n * LDA + seg * 8]) =
            *reinterpret_cast<const uint4*>(BtHi + g);
        *reinterpret_cast<uint4*>(&sBl[n * LDA + seg * 8]) =
            *reinterpret_cast<const uint4*>(BtLo + g);
      }
    }
    __syncthreads();
    {  // MFMA: Ah*Bh + Al*Bh + Ah*Bl
      bf16x8 bh[NF], bl[NF];
#pragma unroll
      for (int nf = 0; nf < NF; ++nf) {
        int bn = wave * (BN / 4) + nf * 16 + fr;
        bh[nf] = *reinterpret_cast<const bf16x8*>(&sBh[bn * LDA + fk]);
        bl[nf] = *reinterpret_cast<const bf16x8*>(&sBl[bn * LDA + fk]);
      }
#pragma unroll
      for (int mf = 0; mf < 4; ++mf) {
        bf16x8 ah = *reinterpret_cast<const bf16x8*>(&sAh[(mf * 16 + fr) * LDA + fk]);
        bf16x8 al = *reinterpret_cast<const bf16x8*>(&sAl[(mf * 16 + fr) * LDA + fk]);
#pragma unroll
        for (int nf = 0; nf < NF; ++nf) {
          acc[mf][nf] = __builtin_amdgcn_mfma_f32_16x16x32_bf16(ah, bh[nf], acc[mf][nf], 0, 0, 0);
          acc[mf][nf] = __builtin_amdgcn_mfma_f32_16x16x32_bf16(al, bh[nf], acc[mf][nf], 0, 0, 0);
          acc[mf][nf] = __builtin_amdgcn_mfma_f32_16x16x32_bf16(ah, bl[nf], acc[mf][nf], 0, 0, 0);
        }
      }
    }
    __syncthreads();
  }
  // epilogue: D[i][j], j = lane%16, i = 4*(lane/16)+reg
#pragma unroll
  for (int mf = 0; mf < 4; ++mf) {
#pragma unroll
    for (int nf = 0; nf < NF; ++nf) {
      int col = wave * (BN / 4) + nf * 16 + fr;
      float bb = bias[col];
#pragma unroll
      for (int r = 0; r < 4; ++r) {
        int grow = m0 + mf * 16 + (lane >> 4) * 4 + r;
        if (grow < rows) {
          float v = acc[mf][nf][r] + bb;
          if (relu) v = fmaxf(v, 0.f);
          C[(size_t)grow * BN + col] = v;
          if (Cb) Cb[(size_t)grow * BN + col] = f2bf(v);
        }
      }
    }
  }
}

// ------------------------------------------------------------- PairNorm
__global__ __launch_bounds__(256) void stats_kernel(const float* __restrict__ x, int N,
                                                    int F, int logF,
                                                    double* __restrict__ colsum,
                                                    double* __restrict__ sumsq) {
  int t = threadIdx.x;
  int col = t & (F - 1);
  int g = t >> logF;
  int G = 256 >> logF;
  float cs = 0.f, ss = 0.f;
  for (int row = blockIdx.x * G + g; row < N; row += gridDim.x * G) {
    float v = x[(size_t)row * F + col];
    cs += v;
    ss = fmaf(v, v, ss);
  }
  __shared__ float scs[256], sss[256];
  scs[t] = cs;
  sss[t] = ss;
  __syncthreads();
  if (t < F) {
    float s = 0.f;
    for (int gg = 0; gg < G; ++gg) s += scs[gg * F + t];
    atomicAdd(&colsum[t], (double)s);
  }
  for (int off = 128; off > 0; off >>= 1) {
    if (t < off) sss[t] += sss[t + off];
    __syncthreads();
  }
  if (t == 0) atomicAdd(sumsq, (double)sss[0]);
}

__global__ __launch_bounds__(128) void finalize_kernel(const double* __restrict__ colsum,
                                                       const double* __restrict__ sumsq,
                                                       int N, int F, float* __restrict__ mu,
                                                       float* __restrict__ scale) {
  int t = threadIdx.x;
  __shared__ double sm[128];
  double m = 0.0;
  if (t < F) {
    m = colsum[t] / (double)N;
    mu[t] = (float)m;
  }
  sm[t] = m * m;
  __syncthreads();
  for (int off = 64; off > 0; off >>= 1) {
    if (t < off) sm[t] += sm[t + off];
    __syncthreads();
  }
  if (t == 0) {
    double var = (sumsq[0] - (double)N * sm[0]) / (double)N;
    scale[0] = (float)(1.0 / sqrt(1e-5 + var));
  }
}

__global__ void apply_kernel(float* __restrict__ x, const float* __restrict__ mu,
                             const float* __restrict__ scale, int total4, int F,
                             uint2* __restrict__ xb) {
  int i = blockIdx.x * blockDim.x + threadIdx.x;
  int stride = gridDim.x * blockDim.x;
  float s = scale[0];
  float4* xv = reinterpret_cast<float4*>(x);
  const float4* muv = reinterpret_cast<const float4*>(mu);
  int nmu = F >> 2;
  for (int idx = i; idx < total4; idx += stride) {
    float4 v = xv[idx];
    float4 m = muv[idx & (nmu - 1)];
    v.x = (v.x - m.x) * s;
    v.y = (v.y - m.y) * s;
    v.z = (v.z - m.z) * s;
    v.w = (v.w - m.w) * s;
    xv[idx] = v;
    if (xb) {
      uint2 pk;
      pk.x = (unsigned int)f2bf(v.x) | ((unsigned int)f2bf(v.y) << 16);
      pk.y = (unsigned int)f2bf(v.z) | ((unsigned int)f2bf(v.w) << 16);
      xb[idx] = pk;
    }
  }
}

// ---------------------------------------------------------------- launcher
extern "C" void kernel_launch(void* const* d_in, const int* in_sizes, int n_in,
                              void* d_out, int out_size, void* d_ws, size_t ws_size,
                              hipStream_t stream) {
  const float* xin    = (const float*)d_in[0];
  const float* W_proj = (const float*)d_in[1];
  const float* b_proj = (const float*)d_in[2];
  const float* basis1 = (const float*)d_in[3];
  const float* comp1  = (const float*)d_in[4];
  const float* root1  = (const float*)d_in[5];
  const float* bias1  = (const float*)d_in[6];
  const float* basis2 = (const float*)d_in[7];
  const float* comp2  = (const float*)d_in[8];
  const float* root2  = (const float*)d_in[9];
  const float* bias2  = (const float*)d_in[10];
  const int*   ei     = (const int*)d_in[11];
  const int*   et     = (const int*)d_in[12];

  const int N  = in_sizes[0] / HID;   // 100000
  const int E  = in_sizes[12];        // 1600000
  const int F2 = in_sizes[10];        // 64
  const int KTOT = NBASIS * HID + HID;  // 640

  float* outp = (float*)d_out;                 // [N, F2]
  float* h0   = outp + (size_t)N * F2;         // [N, 128]
  float* h1   = h0 + (size_t)N * HID;          // [N, 128]

  char* ws = (char*)d_ws;
  size_t off = 0;
  auto alloc = [&](size_t bytes) -> void* {
    void* p = ws + off;
    off = (off + bytes + 255) & ~(size_t)255;
    return p;
  };
  int*    cnt      = (int*)alloc((size_t)N * NREL * 4);
  int*    rowptr   = (int*)alloc(((size_t)N + 1) * 4);
  int*    cursor   = (int*)alloc((size_t)N * 4);
  int*    csr      = (int*)alloc((size_t)E * 4);
  int*    blocksum = (int*)alloc(1024 * 4);
  int*    blockoff = (int*)alloc(1024 * 4);
  double* stats    = (double*)alloc(129 * 8);
  float*  mu       = (float*)alloc(128 * 4);
  float*  scale    = (float*)alloc(4);
  unsigned short* h0b = (unsigned short*)alloc((size_t)N * HID * 2);
  unsigned short* h1b = (unsigned short*)alloc((size_t)N * HID * 2);
  unsigned short* btPH = (unsigned short*)alloc((size_t)HID * HID * 2);
  unsigned short* btPL = (unsigned short*)alloc((size_t)HID * HID * 2);
  unsigned short* bt1H = (unsigned short*)alloc((size_t)HID * KTOT * 2);
  unsigned short* bt1L = (unsigned short*)alloc((size_t)HID * KTOT * 2);
  unsigned short* bt2H = (unsigned short*)alloc((size_t)F2 * KTOT * 2);
  unsigned short* bt2L = (unsigned short*)alloc((size_t)F2 * KTOT * 2);
  float*  aggB     = (float*)(ws + off);
  size_t avail = (ws_size > off) ? ws_size - off : 0;
  size_t rowBytes = (size_t)(NBASIS * HID) * 4;
  long chunk_rows = N;
  if (avail < (size_t)N * rowBytes) chunk_rows = (long)(avail / rowBytes);
  if (chunk_rows < 64) chunk_rows = 64;

  // 0. weight prep: transpose + bf16 hi/lo split (tiny)
  prep_kernel<<<(HID * HID + 255) / 256, 256, 0, stream>>>(W_proj, HID, W_proj, HID,
                                                           HID, btPH, btPL);
  prep_kernel<<<(KTOT * HID + 255) / 256, 256, 0, stream>>>(basis1, NBASIS * HID, root1,
                                                            KTOT, HID, bt1H, bt1L);
  prep_kernel<<<(KTOT * F2 + 255) / 256, 256, 0, stream>>>(basis2, NBASIS * HID, root2,
                                                           KTOT, F2, bt2H, bt2L);

  // 1. h0 = relu(x @ W_proj + b_proj); also write bf16 copy h0b
  mgemm_kernel<HID><<<(N + 63) / 64, 256, 0, stream>>>(
      xin, HID, nullptr, 0, btPH, btPL, b_proj, h0, h0b, N, 1);

  // 2. CSR build (shared by both layers)
  hipMemsetAsync(cnt, 0, (size_t)N * NREL * 4, stream);
  hist_kernel<<<2048, 256, 0, stream>>>(ei, et, cnt, E);
  int nb = (N + 255) / 256;
  scanA_kernel<<<nb, 256, 0, stream>>>(cnt, rowptr, blocksum, N);
  scanB_kernel<<<1, 1024, 0, stream>>>(blocksum, blockoff, nb);
  scanC_kernel<<<nb, 256, 0, stream>>>(rowptr, blockoff, cursor, N);
  scatter_kernel<<<2048, 256, 0, stream>>>(ei, et, cursor, csr, E);

  // 3. layer 1: RGCN -> relu (h1), then pairnorm in place (+ bf16 copy h1b)
  for (long r0 = 0; r0 < N; r0 += chunk_rows) {
    long rows = (N - r0 < chunk_rows) ? (N - r0) : chunk_rows;
    agg_kernel<<<(int)((rows + 3) / 4), 256, 0, stream>>>(h0b, rowptr, csr, cnt, comp1,
                                                          aggB, (int)r0, (int)rows);
    mgemm_kernel<HID><<<(int)((rows + 63) / 64), 256, 0, stream>>>(
        aggB, NBASIS * HID, h0 + r0 * HID, HID, bt1H, bt1L, bias1, h1 + r0 * HID,
        nullptr, (int)rows, 1);
  }
  hipMemsetAsync(stats, 0, 129 * 8, stream);
  stats_kernel<<<512, 256, 0, stream>>>(h1, N, HID, 7, stats, stats + 128);
  finalize_kernel<<<1, 128, 0, stream>>>(stats, stats + 128, N, HID, mu, scale);
  apply_kernel<<<2048, 256, 0, stream>>>(h1, mu, scale, N * HID / 4, HID, (uint2*)h1b);

  // 4. layer 2: RGCN (out), then pairnorm in place
  for (long r0 = 0; r0 < N; r0 += chunk_rows) {
    long rows = (N - r0 < chunk_rows) ? (N - r0) : chunk_rows;
    agg_kernel<<<(int)((rows + 3) / 4), 256, 0, stream>>>(h1b, rowptr, csr, cnt, comp2,
                                                          aggB, (int)r0, (int)rows);
    mgemm_kernel<64><<<(int)((rows + 63) / 64), 256, 0, stream>>>(
        aggB, NBASIS * HID, h1 + r0 * HID, HID, bt2H, bt2L, bias2, outp + r0 * F2,
        nullptr, (int)rows, 0);
  }
  hipMemsetAsync(stats, 0, 129 * 8, stream);
  stats_kernel<<<512, 256, 0, stream>>>(outp, N, F2, 6, stats, stats + 128);
  finalize_kernel<<<1, 128, 0, stream>>>(stats, stats + 128, N, F2, mu, scale);
  apply_kernel<<<2048, 256, 0, stream>>>(outp, mu, scale, N * F2 / 4, F2, nullptr);
}

// Round 10
// 833.814 us; speedup vs baseline: 2.6668x; 1.2337x over previous
//
#include <hip/hip_runtime.h>

#define HID 128
#define NREL 8
#define NBASIS 4

typedef __attribute__((ext_vector_type(8))) short bf16x8;
typedef __attribute__((ext_vector_type(4))) float f32x4;

__device__ __forceinline__ float bf2f(unsigned short u) {
  return __uint_as_float(((unsigned int)u) << 16);
}
__device__ __forceinline__ unsigned short f2bf(float f) {
  unsigned int u = __float_as_uint(f);
  u += 0x7fffu + ((u >> 16) & 1u);
  return (unsigned short)(u >> 16);
}
__device__ __forceinline__ unsigned int pack2bf(float a, float b) {
  return (unsigned int)f2bf(a) | ((unsigned int)f2bf(b) << 16);
}
// split fp32x4 into hi/lo bf16 pairs, packed 2-per-u32
__device__ __forceinline__ void split_pack(float4 v, uint2& hp, uint2& lp) {
  unsigned short h0 = f2bf(v.x), h1 = f2bf(v.y), h2 = f2bf(v.z), h3 = f2bf(v.w);
  hp = make_uint2((unsigned)h0 | ((unsigned)h1 << 16),
                  (unsigned)h2 | ((unsigned)h3 << 16));
  unsigned short l0 = f2bf(v.x - bf2f(h0)), l1 = f2bf(v.y - bf2f(h1));
  unsigned short l2 = f2bf(v.z - bf2f(h2)), l3 = f2bf(v.w - bf2f(h3));
  lp = make_uint2((unsigned)l0 | ((unsigned)l1 << 16),
                  (unsigned)l2 | ((unsigned)l3 << 16));
}

// ---------------------------------------------------------------- CSR build
__global__ void hist_kernel(const int* __restrict__ ei, const int* __restrict__ et,
                            int* __restrict__ cnt, int E) {
  int i = blockIdx.x * blockDim.x + threadIdx.x;
  int stride = gridDim.x * blockDim.x;
  for (int e = i; e < E; e += stride) {
    int dst = ei[E + e];
    int r = et[e];
    atomicAdd(&cnt[dst * NREL + r], 1);
  }
}

__global__ __launch_bounds__(256) void scanA_kernel(const int* __restrict__ cnt,
                                                    int* __restrict__ rowptr,
                                                    int* __restrict__ blocksum, int N) {
  int t = threadIdx.x;
  int n = blockIdx.x * 256 + t;
  int deg = 0;
  if (n < N) {
#pragma unroll
    for (int r = 0; r < NREL; ++r) deg += cnt[n * NREL + r];
  }
  __shared__ int s[256];
  s[t] = deg;
  __syncthreads();
  for (int off = 1; off < 256; off <<= 1) {
    int v = (t >= off) ? s[t - off] : 0;
    __syncthreads();
    s[t] += v;
    __syncthreads();
  }
  if (n < N) rowptr[n + 1] = s[t];
  if (t == 255) blocksum[blockIdx.x] = s[255];
}

__global__ __launch_bounds__(1024) void scanB_kernel(const int* __restrict__ bs,
                                                     int* __restrict__ bo, int nb) {
  int t = threadIdx.x;
  __shared__ int s[1024];
  int v = (t < nb) ? bs[t] : 0;
  s[t] = v;
  __syncthreads();
  for (int off = 1; off < 1024; off <<= 1) {
    int u = (t >= off) ? s[t - off] : 0;
    __syncthreads();
    s[t] += u;
    __syncthreads();
  }
  if (t < nb) bo[t] = s[t] - v;  // exclusive block offset
}

__global__ __launch_bounds__(256) void scanC_kernel(int* __restrict__ rowptr,
                                                    const int* __restrict__ bo,
                                                    int* __restrict__ cursor, int N) {
  int n = blockIdx.x * 256 + threadIdx.x;
  if (n < N) {
    int v = rowptr[n + 1] + bo[blockIdx.x];
    rowptr[n + 1] = v;
    if (n + 1 < N) cursor[n + 1] = v;
    if (n == 0) { rowptr[0] = 0; cursor[0] = 0; }
  }
}

__global__ void scatter_kernel(const int* __restrict__ ei, const int* __restrict__ et,
                               int* __restrict__ cursor, int* __restrict__ csr, int E) {
  int i = blockIdx.x * blockDim.x + threadIdx.x;
  int stride = gridDim.x * blockDim.x;
  for (int e = i; e < E; e += stride) {
    int dst = ei[E + e];
    int src = ei[e];
    int r = et[e];
    int pos = atomicAdd(&cursor[dst], 1);
    csr[pos] = src | (r << 28);  // src < 2^28, r < 8
  }
}

// ------------------------------------------------ per-node basis aggregation
// One wave per node; lane owns 2 feature columns. bf16 gather, bf16 output.
__global__ __launch_bounds__(256) void agg_kernel(
    const unsigned short* __restrict__ hb, const int* __restrict__ rowptr,
    const int* __restrict__ csr, const int* __restrict__ cnt,
    const float* __restrict__ comp, unsigned short* __restrict__ aggB, int row0,
    int nrows) {
  __shared__ float4 s_w[4][NREL];
  const int wave = threadIdx.x >> 6;
  const int lane = threadIdx.x & 63;
  const int nl = blockIdx.x * 4 + wave;
  const bool active = nl < nrows;
  const int n = row0 + nl;
  if (active && lane < NREL) {
    int r = lane;
    float inv = 1.0f / fmaxf((float)cnt[(size_t)n * NREL + r], 1.0f);
    s_w[wave][r] = make_float4(comp[r * NBASIS + 0] * inv, comp[r * NBASIS + 1] * inv,
                               comp[r * NBASIS + 2] * inv, comp[r * NBASIS + 3] * inv);
  }
  __syncthreads();
  if (!active) return;
  float a00 = 0.f, a01 = 0.f, a10 = 0.f, a11 = 0.f;
  float a20 = 0.f, a21 = 0.f, a30 = 0.f, a31 = 0.f;
  const int e0 = rowptr[n], e1 = rowptr[n + 1];
  int j = e0;
  for (; j + 1 < e1; j += 2) {  // 2 independent gathers in flight
    int pa = csr[j], pb = csr[j + 1];
    unsigned int hva = *reinterpret_cast<const unsigned int*>(
        hb + (size_t)(pa & 0x0FFFFFFF) * HID + lane * 2);
    unsigned int hvb = *reinterpret_cast<const unsigned int*>(
        hb + (size_t)(pb & 0x0FFFFFFF) * HID + lane * 2);
    float4 wa = s_w[wave][((unsigned int)pa) >> 28];
    float4 wb = s_w[wave][((unsigned int)pb) >> 28];
    float loa = bf2f((unsigned short)(hva & 0xffffu));
    float hia = bf2f((unsigned short)(hva >> 16));
    float lob = bf2f((unsigned short)(hvb & 0xffffu));
    float hib = bf2f((unsigned short)(hvb >> 16));
    a00 = fmaf(wa.x, loa, a00); a01 = fmaf(wa.x, hia, a01);
    a10 = fmaf(wa.y, loa, a10); a11 = fmaf(wa.y, hia, a11);
    a20 = fmaf(wa.z, loa, a20); a21 = fmaf(wa.z, hia, a21);
    a30 = fmaf(wa.w, loa, a30); a31 = fmaf(wa.w, hia, a31);
    a00 = fmaf(wb.x, lob, a00); a01 = fmaf(wb.x, hib, a01);
    a10 = fmaf(wb.y, lob, a10); a11 = fmaf(wb.y, hib, a11);
    a20 = fmaf(wb.z, lob, a20); a21 = fmaf(wb.z, hib, a21);
    a30 = fmaf(wb.w, lob, a30); a31 = fmaf(wb.w, hib, a31);
  }
  if (j < e1) {
    int p = csr[j];
    unsigned int hv = *reinterpret_cast<const unsigned int*>(
        hb + (size_t)(p & 0x0FFFFFFF) * HID + lane * 2);
    float4 ww = s_w[wave][((unsigned int)p) >> 28];
    float lo = bf2f((unsigned short)(hv & 0xffffu));
    float hi = bf2f((unsigned short)(hv >> 16));
    a00 = fmaf(ww.x, lo, a00); a01 = fmaf(ww.x, hi, a01);
    a10 = fmaf(ww.y, lo, a10); a11 = fmaf(ww.y, hi, a11);
    a20 = fmaf(ww.z, lo, a20); a21 = fmaf(ww.z, hi, a21);
    a30 = fmaf(ww.w, lo, a30); a31 = fmaf(ww.w, hi, a31);
  }
  // bf16 output: halves write traffic; GEMM consumes bf16 A directly
  unsigned short* o = aggB + (size_t)nl * (NBASIS * HID) + lane * 2;
  *reinterpret_cast<unsigned int*>(o + 0 * HID) = pack2bf(a00, a01);
  *reinterpret_cast<unsigned int*>(o + 1 * HID) = pack2bf(a10, a11);
  *reinterpret_cast<unsigned int*>(o + 2 * HID) = pack2bf(a20, a21);
  *reinterpret_cast<unsigned int*>(o + 3 * HID) = pack2bf(a30, a31);
}

// ----------------------------------------- weight prep: transpose + bf16 split
__global__ __launch_bounds__(256) void prep_kernel(
    const float* __restrict__ Wa, int rowsA, const float* __restrict__ Wb, int K,
    int Ncols, unsigned short* __restrict__ BtHi, unsigned short* __restrict__ BtLo) {
  int i = blockIdx.x * 256 + threadIdx.x;
  if (i >= K * Ncols) return;
  int k = i / Ncols, n = i - k * Ncols;
  float w = (k < rowsA) ? Wa[(size_t)k * Ncols + n]
                        : Wb[(size_t)(k - rowsA) * Ncols + n];
  unsigned short h = f2bf(w);
  BtHi[(size_t)n * K + k] = h;
  BtLo[(size_t)n * K + k] = f2bf(w - bf2f(h));
}

// --------------------------------------------------- MFMA GEMM
// C[m,:BN] = (A1b[m,:k1](bf16) ++ A2[m,:k2](fp32)) @ W + bias.
// A1 native bf16 (no lo term); A2 split hi/lo bf16x3. B pre-split hi/lo.
template <int BN>
__global__ __launch_bounds__(256) void mgemm_kernel(
    const unsigned short* __restrict__ A1b, int k1, const float* __restrict__ A2,
    int k2, const unsigned short* __restrict__ BtHi,
    const unsigned short* __restrict__ BtLo, const float* __restrict__ bias,
    float* __restrict__ C, unsigned short* __restrict__ Cb, int rows, int relu) {
  constexpr int BM = 64, BK = 32;
  constexpr int LDA = BK + 8;  // 80B pitch: 8-row bank period covers all 32 banks
  constexpr int NF = BN / 64;
  __shared__ __align__(16) unsigned short sAh[BM * LDA], sAl[BM * LDA];
  __shared__ __align__(16) unsigned short sBh[BN * LDA], sBl[BN * LDA];
  const int t = threadIdx.x;
  const int wave = t >> 6, lane = t & 63;
  const int fr = lane & 15;
  const int fk = (lane >> 4) * 8;
  const int m0 = blockIdx.x * BM;
  const int ldk = k1 + k2;
  const int nk = ldk >> 5, nk1 = k1 >> 5;
  f32x4 acc[4][NF];
#pragma unroll
  for (int i = 0; i < 4; ++i)
#pragma unroll
    for (int j = 0; j < NF; ++j) acc[i][j] = (f32x4){0.f, 0.f, 0.f, 0.f};

  const int arow = t >> 2, aseg = t & 3;
  for (int kc = 0; kc < nk; ++kc) {
    const bool hasLo = (kc >= nk1);  // wave-uniform
    if (!hasLo) {  // stage A from bf16 source: plain 16B copy
      int kb = kc << 5;
      uint4 v = make_uint4(0u, 0u, 0u, 0u);
      int grow = m0 + arow;
      if (grow < rows)
        v = *reinterpret_cast<const uint4*>(A1b + (size_t)grow * k1 + kb + aseg * 8);
      *reinterpret_cast<uint4*>(&sAh[arow * LDA + aseg * 8]) = v;
    } else {  // stage A from fp32 source: split hi/lo
      int kb = (kc - nk1) << 5;
      float4 v0 = make_float4(0.f, 0.f, 0.f, 0.f), v1 = v0;
      int grow = m0 + arow;
      if (grow < rows) {
        const float* p = A2 + (size_t)grow * k2 + kb + aseg * 8;
        v0 = *reinterpret_cast<const float4*>(p);
        v1 = *reinterpret_cast<const float4*>(p + 4);
      }
      uint2 hp0, lp0, hp1, lp1;
      split_pack(v0, hp0, lp0);
      split_pack(v1, hp1, lp1);
      unsigned short* da = &sAh[arow * LDA + aseg * 8];
      *reinterpret_cast<uint2*>(da) = hp0;
      *reinterpret_cast<uint2*>(da + 4) = hp1;
      unsigned short* dl = &sAl[arow * LDA + aseg * 8];
      *reinterpret_cast<uint2*>(dl) = lp0;
      *reinterpret_cast<uint2*>(dl + 4) = lp1;
    }
    {  // stage B: BN x 32 bf16 hi/lo (pre-transposed in global)
      int k0 = kc << 5;
#pragma unroll
      for (int l = 0; l < (BN * 4) / 256; ++l) {
        int i = t + l * 256;
        int n = i >> 2, seg = i & 3;
        size_t g = (size_t)n * ldk + k0 + seg * 8;
        *reinterpret_cast<uint4*>(&sBh[n * LDA + seg * 8]) =
            *reinterpret_cast<const uint4*>(BtHi + g);
        *reinterpret_cast<uint4*>(&sBl[n * LDA + seg * 8]) =
            *reinterpret_cast<const uint4*>(BtLo + g);
      }
    }
    __syncthreads();
    {
      bf16x8 bh[NF], bl[NF];
#pragma unroll
      for (int nf = 0; nf < NF; ++nf) {
        int bn = wave * (BN / 4) + nf * 16 + fr;
        bh[nf] = *reinterpret_cast<const bf16x8*>(&sBh[bn * LDA + fk]);
        bl[nf] = *reinterpret_cast<const bf16x8*>(&sBl[bn * LDA + fk]);
      }
      if (!hasLo) {  // A native bf16: Ah*Bh + Ah*Bl
#pragma unroll
        for (int mf = 0; mf < 4; ++mf) {
          bf16x8 ah = *reinterpret_cast<const bf16x8*>(&sAh[(mf * 16 + fr) * LDA + fk]);
#pragma unroll
          for (int nf = 0; nf < NF; ++nf) {
            acc[mf][nf] = __builtin_amdgcn_mfma_f32_16x16x32_bf16(ah, bh[nf], acc[mf][nf], 0, 0, 0);
            acc[mf][nf] = __builtin_amdgcn_mfma_f32_16x16x32_bf16(ah, bl[nf], acc[mf][nf], 0, 0, 0);
          }
        }
      } else {  // A split: Ah*Bh + Al*Bh + Ah*Bl
#pragma unroll
        for (int mf = 0; mf < 4; ++mf) {
          bf16x8 ah = *reinterpret_cast<const bf16x8*>(&sAh[(mf * 16 + fr) * LDA + fk]);
          bf16x8 al = *reinterpret_cast<const bf16x8*>(&sAl[(mf * 16 + fr) * LDA + fk]);
#pragma unroll
          for (int nf = 0; nf < NF; ++nf) {
            acc[mf][nf] = __builtin_amdgcn_mfma_f32_16x16x32_bf16(ah, bh[nf], acc[mf][nf], 0, 0, 0);
            acc[mf][nf] = __builtin_amdgcn_mfma_f32_16x16x32_bf16(al, bh[nf], acc[mf][nf], 0, 0, 0);
            acc[mf][nf] = __builtin_amdgcn_mfma_f32_16x16x32_bf16(ah, bl[nf], acc[mf][nf], 0, 0, 0);
          }
        }
      }
    }
    __syncthreads();
  }
#pragma unroll
  for (int mf = 0; mf < 4; ++mf) {
#pragma unroll
    for (int nf = 0; nf < NF; ++nf) {
      int col = wave * (BN / 4) + nf * 16 + fr;
      float bb = bias[col];
#pragma unroll
      for (int r = 0; r < 4; ++r) {
        int grow = m0 + mf * 16 + (lane >> 4) * 4 + r;
        if (grow < rows) {
          float v = acc[mf][nf][r] + bb;
          if (relu) v = fmaxf(v, 0.f);
          C[(size_t)grow * BN + col] = v;
          if (Cb) Cb[(size_t)grow * BN + col] = f2bf(v);
        }
      }
    }
  }
}

// ------------------------------------------------------------- PairNorm
__global__ __launch_bounds__(256) void stats_kernel(const float* __restrict__ x, int N,
                                                    int F, int logF,
                                                    double* __restrict__ colsum,
                                                    double* __restrict__ sumsq) {
  int t = threadIdx.x;
  int col = t & (F - 1);
  int g = t >> logF;
  int G = 256 >> logF;
  float cs = 0.f, ss = 0.f;
  for (int row = blockIdx.x * G + g; row < N; row += gridDim.x * G) {
    float v = x[(size_t)row * F + col];
    cs += v;
    ss = fmaf(v, v, ss);
  }
  __shared__ float scs[256], sss[256];
  scs[t] = cs;
  sss[t] = ss;
  __syncthreads();
  if (t < F) {
    float s = 0.f;
    for (int gg = 0; gg < G; ++gg) s += scs[gg * F + t];
    atomicAdd(&colsum[t], (double)s);
  }
  for (int off = 128; off > 0; off >>= 1) {
    if (t < off) sss[t] += sss[t + off];
    __syncthreads();
  }
  if (t == 0) atomicAdd(sumsq, (double)sss[0]);
}

__global__ __launch_bounds__(128) void finalize_kernel(const double* __restrict__ colsum,
                                                       const double* __restrict__ sumsq,
                                                       int N, int F, float* __restrict__ mu,
                                                       float* __restrict__ scale) {
  int t = threadIdx.x;
  __shared__ double sm[128];
  double m = 0.0;
  if (t < F) {
    m = colsum[t] / (double)N;
    mu[t] = (float)m;
  }
  sm[t] = m * m;
  __syncthreads();
  for (int off = 64; off > 0; off >>= 1) {
    if (t < off) sm[t] += sm[t + off];
    __syncthreads();
  }
  if (t == 0) {
    double var = (sumsq[0] - (double)N * sm[0]) / (double)N;
    scale[0] = (float)(1.0 / sqrt(1e-5 + var));
  }
}

__global__ void apply_kernel(float* __restrict__ x, const float* __restrict__ mu,
                             const float* __restrict__ scale, int total4, int F,
                             uint2* __restrict__ xb) {
  int i = blockIdx.x * blockDim.x + threadIdx.x;
  int stride = gridDim.x * blockDim.x;
  float s = scale[0];
  float4* xv = reinterpret_cast<float4*>(x);
  const float4* muv = reinterpret_cast<const float4*>(mu);
  int nmu = F >> 2;
  for (int idx = i; idx < total4; idx += stride) {
    float4 v = xv[idx];
    float4 m = muv[idx & (nmu - 1)];
    v.x = (v.x - m.x) * s;
    v.y = (v.y - m.y) * s;
    v.z = (v.z - m.z) * s;
    v.w = (v.w - m.w) * s;
    xv[idx] = v;
    if (xb) {
      uint2 pk;
      pk.x = pack2bf(v.x, v.y);
      pk.y = pack2bf(v.z, v.w);
      xb[idx] = pk;
    }
  }
}

// ---------------------------------------------------------------- launcher
extern "C" void kernel_launch(void* const* d_in, const int* in_sizes, int n_in,
                              void* d_out, int out_size, void* d_ws, size_t ws_size,
                              hipStream_t stream) {
  const float* xin    = (const float*)d_in[0];
  const float* W_proj = (const float*)d_in[1];
  const float* b_proj = (const float*)d_in[2];
  const float* basis1 = (const float*)d_in[3];
  const float* comp1  = (const float*)d_in[4];
  const float* root1  = (const float*)d_in[5];
  const float* bias1  = (const float*)d_in[6];
  const float* basis2 = (const float*)d_in[7];
  const float* comp2  = (const float*)d_in[8];
  const float* root2  = (const float*)d_in[9];
  const float* bias2  = (const float*)d_in[10];
  const int*   ei     = (const int*)d_in[11];
  const int*   et     = (const int*)d_in[12];

  const int N  = in_sizes[0] / HID;   // 100000
  const int E  = in_sizes[12];        // 1600000
  const int F2 = in_sizes[10];        // 64
  const int KTOT = NBASIS * HID + HID;  // 640

  float* outp = (float*)d_out;                 // [N, F2]
  float* h0   = outp + (size_t)N * F2;         // [N, 128]
  float* h1   = h0 + (size_t)N * HID;          // [N, 128]

  char* ws = (char*)d_ws;
  size_t off = 0;
  auto alloc = [&](size_t bytes) -> void* {
    void* p = ws + off;
    off = (off + bytes + 255) & ~(size_t)255;
    return p;
  };
  int*    cnt      = (int*)alloc((size_t)N * NREL * 4);
  int*    rowptr   = (int*)alloc(((size_t)N + 1) * 4);
  int*    cursor   = (int*)alloc((size_t)N * 4);
  int*    csr      = (int*)alloc((size_t)E * 4);
  int*    blocksum = (int*)alloc(1024 * 4);
  int*    blockoff = (int*)alloc(1024 * 4);
  double* stats    = (double*)alloc(129 * 8);
  float*  mu       = (float*)alloc(128 * 4);
  float*  scale    = (float*)alloc(4);
  unsigned short* h0b = (unsigned short*)alloc((size_t)N * HID * 2);
  unsigned short* h1b = (unsigned short*)alloc((size_t)N * HID * 2);
  unsigned short* btPH = (unsigned short*)alloc((size_t)HID * HID * 2);
  unsigned short* btPL = (unsigned short*)alloc((size_t)HID * HID * 2);
  unsigned short* bt1H = (unsigned short*)alloc((size_t)HID * KTOT * 2);
  unsigned short* bt1L = (unsigned short*)alloc((size_t)HID * KTOT * 2);
  unsigned short* bt2H = (unsigned short*)alloc((size_t)F2 * KTOT * 2);
  unsigned short* bt2L = (unsigned short*)alloc((size_t)F2 * KTOT * 2);
  unsigned short* aggBb = (unsigned short*)(ws + off);
  size_t avail = (ws_size > off) ? ws_size - off : 0;
  size_t rowBytes = (size_t)(NBASIS * HID) * 2;  // bf16 now
  long chunk_rows = N;
  if (avail < (size_t)N * rowBytes) chunk_rows = (long)(avail / rowBytes);
  if (chunk_rows < 64) chunk_rows = 64;

  // 0. weight prep: transpose + bf16 hi/lo split (tiny)
  prep_kernel<<<(HID * HID + 255) / 256, 256, 0, stream>>>(W_proj, HID, W_proj, HID,
                                                           HID, btPH, btPL);
  prep_kernel<<<(KTOT * HID + 255) / 256, 256, 0, stream>>>(basis1, NBASIS * HID, root1,
                                                            KTOT, HID, bt1H, bt1L);
  prep_kernel<<<(KTOT * F2 + 255) / 256, 256, 0, stream>>>(basis2, NBASIS * HID, root2,
                                                           KTOT, F2, bt2H, bt2L);

  // 1. h0 = relu(x @ W_proj + b_proj); also write bf16 copy h0b
  mgemm_kernel<HID><<<(N + 63) / 64, 256, 0, stream>>>(
      nullptr, 0, xin, HID, btPH, btPL, b_proj, h0, h0b, N, 1);

  // 2. CSR build (shared by both layers)
  hipMemsetAsync(cnt, 0, (size_t)N * NREL * 4, stream);
  hist_kernel<<<2048, 256, 0, stream>>>(ei, et, cnt, E);
  int nb = (N + 255) / 256;
  scanA_kernel<<<nb, 256, 0, stream>>>(cnt, rowptr, blocksum, N);
  scanB_kernel<<<1, 1024, 0, stream>>>(blocksum, blockoff, nb);
  scanC_kernel<<<nb, 256, 0, stream>>>(rowptr, blockoff, cursor, N);
  scatter_kernel<<<2048, 256, 0, stream>>>(ei, et, cursor, csr, E);

  // 3. layer 1: RGCN -> relu (h1), then pairnorm in place (+ bf16 copy h1b)
  for (long r0 = 0; r0 < N; r0 += chunk_rows) {
    long rows = (N - r0 < chunk_rows) ? (N - r0) : chunk_rows;
    agg_kernel<<<(int)((rows + 3) / 4), 256, 0, stream>>>(h0b, rowptr, csr, cnt, comp1,
                                                          aggBb, (int)r0, (int)rows);
    mgemm_kernel<HID><<<(int)((rows + 63) / 64), 256, 0, stream>>>(
        aggBb, NBASIS * HID, h0 + r0 * HID, HID, bt1H, bt1L, bias1, h1 + r0 * HID,
        nullptr, (int)rows, 1);
  }
  hipMemsetAsync(stats, 0, 129 * 8, stream);
  stats_kernel<<<512, 256, 0, stream>>>(h1, N, HID, 7, stats, stats + 128);
  finalize_kernel<<<1, 128, 0, stream>>>(stats, stats + 128, N, HID, mu, scale);
  apply_kernel<<<2048, 256, 0, stream>>>(h1, mu, scale, N * HID / 4, HID, (uint2*)h1b);

  // 4. layer 2: RGCN (out), then pairnorm in place
  for (long r0 = 0; r0 < N; r0 += chunk_rows) {
    long rows = (N - r0 < chunk_rows) ? (N - r0) : chunk_rows;
    agg_kernel<<<(int)((rows + 3) / 4), 256, 0, stream>>>(h1b, rowptr, csr, cnt, comp2,
                                                          aggBb, (int)r0, (int)rows);
    mgemm_kernel<64><<<(int)((rows + 63) / 64), 256, 0, stream>>>(
        aggBb, NBASIS * HID, h1 + r0 * HID, HID, bt2H, bt2L, bias2, outp + r0 * F2,
        nullptr, (int)rows, 0);
  }
  hipMemsetAsync(stats, 0, 129 * 8, stream);
  stats_kernel<<<512, 256, 0, stream>>>(outp, N, F2, 6, stats, stats + 128);
  finalize_kernel<<<1, 128, 0, stream>>>(stats, stats + 128, N, F2, mu, scale);
  apply_kernel<<<2048, 256, 0, stream>>>(outp, mu, scale, N * F2 / 4, F2, nullptr);
}

// Round 11
// 786.360 us; speedup vs baseline: 2.8277x; 1.0603x over previous
//
#include <hip/hip_runtime.h>

#define HID 128
#define NREL 8
#define NBASIS 4

typedef __attribute__((ext_vector_type(8))) short bf16x8;
typedef __attribute__((ext_vector_type(4))) float f32x4;

__device__ __forceinline__ float bf2f(unsigned short u) {
  return __uint_as_float(((unsigned int)u) << 16);
}
__device__ __forceinline__ unsigned short f2bf(float f) {
  unsigned int u = __float_as_uint(f);
  u += 0x7fffu + ((u >> 16) & 1u);
  return (unsigned short)(u >> 16);
}
__device__ __forceinline__ unsigned int pack2bf(float a, float b) {
  return (unsigned int)f2bf(a) | ((unsigned int)f2bf(b) << 16);
}
// split fp32x4 into hi/lo bf16 pairs, packed 2-per-u32
__device__ __forceinline__ void split_pack(float4 v, uint2& hp, uint2& lp) {
  unsigned short h0 = f2bf(v.x), h1 = f2bf(v.y), h2 = f2bf(v.z), h3 = f2bf(v.w);
  hp = make_uint2((unsigned)h0 | ((unsigned)h1 << 16),
                  (unsigned)h2 | ((unsigned)h3 << 16));
  unsigned short l0 = f2bf(v.x - bf2f(h0)), l1 = f2bf(v.y - bf2f(h1));
  unsigned short l2 = f2bf(v.z - bf2f(h2)), l3 = f2bf(v.w - bf2f(h3));
  lp = make_uint2((unsigned)l0 | ((unsigned)l1 << 16),
                  (unsigned)l2 | ((unsigned)l3 << 16));
}

// ---------------------------------------------------------------- CSR build
__global__ void hist_kernel(const int* __restrict__ ei, const int* __restrict__ et,
                            int* __restrict__ cnt, int E) {
  int i = blockIdx.x * blockDim.x + threadIdx.x;
  int stride = gridDim.x * blockDim.x;
  for (int e = i; e < E; e += stride) {
    int dst = ei[E + e];
    int r = et[e];
    atomicAdd(&cnt[dst * NREL + r], 1);
  }
}

__global__ __launch_bounds__(256) void scanA_kernel(const int* __restrict__ cnt,
                                                    int* __restrict__ rowptr,
                                                    int* __restrict__ blocksum, int N) {
  int t = threadIdx.x;
  int n = blockIdx.x * 256 + t;
  int deg = 0;
  if (n < N) {
#pragma unroll
    for (int r = 0; r < NREL; ++r) deg += cnt[n * NREL + r];
  }
  __shared__ int s[256];
  s[t] = deg;
  __syncthreads();
  for (int off = 1; off < 256; off <<= 1) {
    int v = (t >= off) ? s[t - off] : 0;
    __syncthreads();
    s[t] += v;
    __syncthreads();
  }
  if (n < N) rowptr[n + 1] = s[t];
  if (t == 255) blocksum[blockIdx.x] = s[255];
}

__global__ __launch_bounds__(1024) void scanB_kernel(const int* __restrict__ bs,
                                                     int* __restrict__ bo, int nb) {
  int t = threadIdx.x;
  __shared__ int s[1024];
  int v = (t < nb) ? bs[t] : 0;
  s[t] = v;
  __syncthreads();
  for (int off = 1; off < 1024; off <<= 1) {
    int u = (t >= off) ? s[t - off] : 0;
    __syncthreads();
    s[t] += u;
    __syncthreads();
  }
  if (t < nb) bo[t] = s[t] - v;  // exclusive block offset
}

__global__ __launch_bounds__(256) void scanC_kernel(int* __restrict__ rowptr,
                                                    const int* __restrict__ bo,
                                                    int* __restrict__ cursor, int N) {
  int n = blockIdx.x * 256 + threadIdx.x;
  if (n < N) {
    int v = rowptr[n + 1] + bo[blockIdx.x];
    rowptr[n + 1] = v;
    if (n + 1 < N) cursor[n + 1] = v;
    if (n == 0) { rowptr[0] = 0; cursor[0] = 0; }
  }
}

// dst-partitioned scatter: block-group g = blockIdx&7 handles dst range g.
// Each group's csr write window (~800KB) stays L2-resident on one XCD
// (blockIdx%8 -> XCD heuristic; correctness is mapping-independent).
__global__ __launch_bounds__(256) void scatter_kernel(const int* __restrict__ ei,
                                                      const int* __restrict__ et,
                                                      int* __restrict__ cursor,
                                                      int* __restrict__ csr, int E,
                                                      int N) {
  const int part = blockIdx.x & 7;
  const int pn = (N + 7) >> 3;
  const int lo = part * pn;
  const int hi = (lo + pn < N) ? lo + pn : N;
  int i = (blockIdx.x >> 3) * blockDim.x + threadIdx.x;
  int stride = (gridDim.x >> 3) * blockDim.x;
  for (int e = i; e < E; e += stride) {
    int dst = ei[E + e];
    if (dst >= lo && dst < hi) {
      int src = ei[e];
      int r = et[e];
      int pos = atomicAdd(&cursor[dst], 1);
      csr[pos] = src | (r << 28);  // src < 2^28, r < 8
    }
  }
}

// ------------------------------------------------ per-node basis aggregation
// One wave per node; lane owns 2 feature columns. bf16 gather, bf16 output.
__global__ __launch_bounds__(256) void agg_kernel(
    const unsigned short* __restrict__ hb, const int* __restrict__ rowptr,
    const int* __restrict__ csr, const int* __restrict__ cnt,
    const float* __restrict__ comp, unsigned short* __restrict__ aggB, int row0,
    int nrows) {
  __shared__ float4 s_w[4][NREL];
  const int wave = threadIdx.x >> 6;
  const int lane = threadIdx.x & 63;
  const int nl = blockIdx.x * 4 + wave;
  const bool active = nl < nrows;
  const int n = row0 + nl;
  if (active && lane < NREL) {
    int r = lane;
    float inv = 1.0f / fmaxf((float)cnt[(size_t)n * NREL + r], 1.0f);
    s_w[wave][r] = make_float4(comp[r * NBASIS + 0] * inv, comp[r * NBASIS + 1] * inv,
                               comp[r * NBASIS + 2] * inv, comp[r * NBASIS + 3] * inv);
  }
  __syncthreads();
  if (!active) return;
  float a00 = 0.f, a01 = 0.f, a10 = 0.f, a11 = 0.f;
  float a20 = 0.f, a21 = 0.f, a30 = 0.f, a31 = 0.f;
  const int e0 = rowptr[n], e1 = rowptr[n + 1];
  int j = e0;
  for (; j + 1 < e1; j += 2) {  // 2 independent gathers in flight
    int pa = csr[j], pb = csr[j + 1];
    unsigned int hva = *reinterpret_cast<const unsigned int*>(
        hb + (size_t)(pa & 0x0FFFFFFF) * HID + lane * 2);
    unsigned int hvb = *reinterpret_cast<const unsigned int*>(
        hb + (size_t)(pb & 0x0FFFFFFF) * HID + lane * 2);
    float4 wa = s_w[wave][((unsigned int)pa) >> 28];
    float4 wb = s_w[wave][((unsigned int)pb) >> 28];
    float loa = bf2f((unsigned short)(hva & 0xffffu));
    float hia = bf2f((unsigned short)(hva >> 16));
    float lob = bf2f((unsigned short)(hvb & 0xffffu));
    float hib = bf2f((unsigned short)(hvb >> 16));
    a00 = fmaf(wa.x, loa, a00); a01 = fmaf(wa.x, hia, a01);
    a10 = fmaf(wa.y, loa, a10); a11 = fmaf(wa.y, hia, a11);
    a20 = fmaf(wa.z, loa, a20); a21 = fmaf(wa.z, hia, a21);
    a30 = fmaf(wa.w, loa, a30); a31 = fmaf(wa.w, hia, a31);
    a00 = fmaf(wb.x, lob, a00); a01 = fmaf(wb.x, hib, a01);
    a10 = fmaf(wb.y, lob, a10); a11 = fmaf(wb.y, hib, a11);
    a20 = fmaf(wb.z, lob, a20); a21 = fmaf(wb.z, hib, a21);
    a30 = fmaf(wb.w, lob, a30); a31 = fmaf(wb.w, hib, a31);
  }
  if (j < e1) {
    int p = csr[j];
    unsigned int hv = *reinterpret_cast<const unsigned int*>(
        hb + (size_t)(p & 0x0FFFFFFF) * HID + lane * 2);
    float4 ww = s_w[wave][((unsigned int)p) >> 28];
    float lo = bf2f((unsigned short)(hv & 0xffffu));
    float hi = bf2f((unsigned short)(hv >> 16));
    a00 = fmaf(ww.x, lo, a00); a01 = fmaf(ww.x, hi, a01);
    a10 = fmaf(ww.y, lo, a10); a11 = fmaf(ww.y, hi, a11);
    a20 = fmaf(ww.z, lo, a20); a21 = fmaf(ww.z, hi, a21);
    a30 = fmaf(ww.w, lo, a30); a31 = fmaf(ww.w, hi, a31);
  }
  // bf16 output: halves write traffic; GEMM consumes bf16 A directly
  unsigned short* o = aggB + (size_t)nl * (NBASIS * HID) + lane * 2;
  *reinterpret_cast<unsigned int*>(o + 0 * HID) = pack2bf(a00, a01);
  *reinterpret_cast<unsigned int*>(o + 1 * HID) = pack2bf(a10, a11);
  *reinterpret_cast<unsigned int*>(o + 2 * HID) = pack2bf(a20, a21);
  *reinterpret_cast<unsigned int*>(o + 3 * HID) = pack2bf(a30, a31);
}

// ----------------------------------------- weight prep: transpose + bf16 split
__global__ __launch_bounds__(256) void prep_kernel(
    const float* __restrict__ Wa, int rowsA, const float* __restrict__ Wb, int K,
    int Ncols, unsigned short* __restrict__ BtHi, unsigned short* __restrict__ BtLo) {
  int i = blockIdx.x * 256 + threadIdx.x;
  if (i >= K * Ncols) return;
  int k = i / Ncols, n = i - k * Ncols;
  float w = (k < rowsA) ? Wa[(size_t)k * Ncols + n]
                        : Wb[(size_t)(k - rowsA) * Ncols + n];
  unsigned short h = f2bf(w);
  BtHi[(size_t)n * K + k] = h;
  BtLo[(size_t)n * K + k] = f2bf(w - bf2f(h));
}

// --------------------------------------------------- MFMA GEMM
// C[m,:BN] = (A1b[m,:k1](bf16) ++ A2[m,:k2](fp32)) @ W + bias.
// A1 native bf16 (no lo term); A2 split hi/lo bf16x3. B pre-split hi/lo.
template <int BN>
__global__ __launch_bounds__(256) void mgemm_kernel(
    const unsigned short* __restrict__ A1b, int k1, const float* __restrict__ A2,
    int k2, const unsigned short* __restrict__ BtHi,
    const unsigned short* __restrict__ BtLo, const float* __restrict__ bias,
    float* __restrict__ C, unsigned short* __restrict__ Cb, int rows, int relu) {
  constexpr int BM = 64, BK = 32;
  constexpr int LDA = BK + 8;  // 80B pitch: 8-row bank period covers all 32 banks
  constexpr int NF = BN / 64;
  __shared__ __align__(16) unsigned short sAh[BM * LDA], sAl[BM * LDA];
  __shared__ __align__(16) unsigned short sBh[BN * LDA], sBl[BN * LDA];
  const int t = threadIdx.x;
  const int wave = t >> 6, lane = t & 63;
  const int fr = lane & 15;
  const int fk = (lane >> 4) * 8;
  const int m0 = blockIdx.x * BM;
  const int ldk = k1 + k2;
  const int nk = ldk >> 5, nk1 = k1 >> 5;
  f32x4 acc[4][NF];
#pragma unroll
  for (int i = 0; i < 4; ++i)
#pragma unroll
    for (int j = 0; j < NF; ++j) acc[i][j] = (f32x4){0.f, 0.f, 0.f, 0.f};

  const int arow = t >> 2, aseg = t & 3;
  for (int kc = 0; kc < nk; ++kc) {
    const bool hasLo = (kc >= nk1);  // wave-uniform
    if (!hasLo) {  // stage A from bf16 source: plain 16B copy
      int kb = kc << 5;
      uint4 v = make_uint4(0u, 0u, 0u, 0u);
      int grow = m0 + arow;
      if (grow < rows)
        v = *reinterpret_cast<const uint4*>(A1b + (size_t)grow * k1 + kb + aseg * 8);
      *reinterpret_cast<uint4*>(&sAh[arow * LDA + aseg * 8]) = v;
    } else {  // stage A from fp32 source: split hi/lo
      int kb = (kc - nk1) << 5;
      float4 v0 = make_float4(0.f, 0.f, 0.f, 0.f), v1 = v0;
      int grow = m0 + arow;
      if (grow < rows) {
        const float* p = A2 + (size_t)grow * k2 + kb + aseg * 8;
        v0 = *reinterpret_cast<const float4*>(p);
        v1 = *reinterpret_cast<const float4*>(p + 4);
      }
      uint2 hp0, lp0, hp1, lp1;
      split_pack(v0, hp0, lp0);
      split_pack(v1, hp1, lp1);
      unsigned short* da = &sAh[arow * LDA + aseg * 8];
      *reinterpret_cast<uint2*>(da) = hp0;
      *reinterpret_cast<uint2*>(da + 4) = hp1;
      unsigned short* dl = &sAl[arow * LDA + aseg * 8];
      *reinterpret_cast<uint2*>(dl) = lp0;
      *reinterpret_cast<uint2*>(dl + 4) = lp1;
    }
    {  // stage B: BN x 32 bf16 hi/lo (pre-transposed in global)
      int k0 = kc << 5;
#pragma unroll
      for (int l = 0; l < (BN * 4) / 256; ++l) {
        int i = t + l * 256;
        int n = i >> 2, seg = i & 3;
        size_t g = (size_t)n * ldk + k0 + seg * 8;
        *reinterpret_cast<uint4*>(&sBh[n * LDA + seg * 8]) =
            *reinterpret_cast<const uint4*>(BtHi + g);
        *reinterpret_cast<uint4*>(&sBl[n * LDA + seg * 8]) =
            *reinterpret_cast<const uint4*>(BtLo + g);
      }
    }
    __syncthreads();
    {
      bf16x8 bh[NF], bl[NF];
#pragma unroll
      for (int nf = 0; nf < NF; ++nf) {
        int bn = wave * (BN / 4) + nf * 16 + fr;
        bh[nf] = *reinterpret_cast<const bf16x8*>(&sBh[bn * LDA + fk]);
        bl[nf] = *reinterpret_cast<const bf16x8*>(&sBl[bn * LDA + fk]);
      }
      if (!hasLo) {  // A native bf16: Ah*Bh + Ah*Bl
#pragma unroll
        for (int mf = 0; mf < 4; ++mf) {
          bf16x8 ah = *reinterpret_cast<const bf16x8*>(&sAh[(mf * 16 + fr) * LDA + fk]);
#pragma unroll
          for (int nf = 0; nf < NF; ++nf) {
            acc[mf][nf] = __builtin_amdgcn_mfma_f32_16x16x32_bf16(ah, bh[nf], acc[mf][nf], 0, 0, 0);
            acc[mf][nf] = __builtin_amdgcn_mfma_f32_16x16x32_bf16(ah, bl[nf], acc[mf][nf], 0, 0, 0);
          }
        }
      } else {  // A split: Ah*Bh + Al*Bh + Ah*Bl
#pragma unroll
        for (int mf = 0; mf < 4; ++mf) {
          bf16x8 ah = *reinterpret_cast<const bf16x8*>(&sAh[(mf * 16 + fr) * LDA + fk]);
          bf16x8 al = *reinterpret_cast<const bf16x8*>(&sAl[(mf * 16 + fr) * LDA + fk]);
#pragma unroll
          for (int nf = 0; nf < NF; ++nf) {
            acc[mf][nf] = __builtin_amdgcn_mfma_f32_16x16x32_bf16(ah, bh[nf], acc[mf][nf], 0, 0, 0);
            acc[mf][nf] = __builtin_amdgcn_mfma_f32_16x16x32_bf16(al, bh[nf], acc[mf][nf], 0, 0, 0);
            acc[mf][nf] = __builtin_amdgcn_mfma_f32_16x16x32_bf16(ah, bl[nf], acc[mf][nf], 0, 0, 0);
          }
        }
      }
    }
    __syncthreads();
  }
#pragma unroll
  for (int mf = 0; mf < 4; ++mf) {
#pragma unroll
    for (int nf = 0; nf < NF; ++nf) {
      int col = wave * (BN / 4) + nf * 16 + fr;
      float bb = bias[col];
#pragma unroll
      for (int r = 0; r < 4; ++r) {
        int grow = m0 + mf * 16 + (lane >> 4) * 4 + r;
        if (grow < rows) {
          float v = acc[mf][nf][r] + bb;
          if (relu) v = fmaxf(v, 0.f);
          C[(size_t)grow * BN + col] = v;
          if (Cb) Cb[(size_t)grow * BN + col] = f2bf(v);
        }
      }
    }
  }
}

// ------------------------------------------------------------- PairNorm
__global__ __launch_bounds__(256) void stats_kernel(const float* __restrict__ x, int N,
                                                    int F, int logF,
                                                    double* __restrict__ colsum,
                                                    double* __restrict__ sumsq) {
  int t = threadIdx.x;
  int col = t & (F - 1);
  int g = t >> logF;
  int G = 256 >> logF;
  float cs = 0.f, ss = 0.f;
  for (int row = blockIdx.x * G + g; row < N; row += gridDim.x * G) {
    float v = x[(size_t)row * F + col];
    cs += v;
    ss = fmaf(v, v, ss);
  }
  __shared__ float scs[256], sss[256];
  scs[t] = cs;
  sss[t] = ss;
  __syncthreads();
  if (t < F) {
    float s = 0.f;
    for (int gg = 0; gg < G; ++gg) s += scs[gg * F + t];
    atomicAdd(&colsum[t], (double)s);
  }
  for (int off = 128; off > 0; off >>= 1) {
    if (t < off) sss[t] += sss[t + off];
    __syncthreads();
  }
  if (t == 0) atomicAdd(sumsq, (double)sss[0]);
}

__global__ __launch_bounds__(128) void finalize_kernel(const double* __restrict__ colsum,
                                                       const double* __restrict__ sumsq,
                                                       int N, int F, float* __restrict__ mu,
                                                       float* __restrict__ scale) {
  int t = threadIdx.x;
  __shared__ double sm[128];
  double m = 0.0;
  if (t < F) {
    m = colsum[t] / (double)N;
    mu[t] = (float)m;
  }
  sm[t] = m * m;
  __syncthreads();
  for (int off = 64; off > 0; off >>= 1) {
    if (t < off) sm[t] += sm[t + off];
    __syncthreads();
  }
  if (t == 0) {
    double var = (sumsq[0] - (double)N * sm[0]) / (double)N;
    scale[0] = (float)(1.0 / sqrt(1e-5 + var));
  }
}

__global__ void apply_kernel(float* __restrict__ x, const float* __restrict__ mu,
                             const float* __restrict__ scale, int total4, int F,
                             uint2* __restrict__ xb) {
  int i = blockIdx.x * blockDim.x + threadIdx.x;
  int stride = gridDim.x * blockDim.x;
  float s = scale[0];
  float4* xv = reinterpret_cast<float4*>(x);
  const float4* muv = reinterpret_cast<const float4*>(mu);
  int nmu = F >> 2;
  for (int idx = i; idx < total4; idx += stride) {
    float4 v = xv[idx];
    float4 m = muv[idx & (nmu - 1)];
    v.x = (v.x - m.x) * s;
    v.y = (v.y - m.y) * s;
    v.z = (v.z - m.z) * s;
    v.w = (v.w - m.w) * s;
    xv[idx] = v;
    if (xb) {
      uint2 pk;
      pk.x = pack2bf(v.x, v.y);
      pk.y = pack2bf(v.z, v.w);
      xb[idx] = pk;
    }
  }
}

// ---------------------------------------------------------------- launcher
extern "C" void kernel_launch(void* const* d_in, const int* in_sizes, int n_in,
                              void* d_out, int out_size, void* d_ws, size_t ws_size,
                              hipStream_t stream) {
  const float* xin    = (const float*)d_in[0];
  const float* W_proj = (const float*)d_in[1];
  const float* b_proj = (const float*)d_in[2];
  const float* basis1 = (const float*)d_in[3];
  const float* comp1  = (const float*)d_in[4];
  const float* root1  = (const float*)d_in[5];
  const float* bias1  = (const float*)d_in[6];
  const float* basis2 = (const float*)d_in[7];
  const float* comp2  = (const float*)d_in[8];
  const float* root2  = (const float*)d_in[9];
  const float* bias2  = (const float*)d_in[10];
  const int*   ei     = (const int*)d_in[11];
  const int*   et     = (const int*)d_in[12];

  const int N  = in_sizes[0] / HID;   // 100000
  const int E  = in_sizes[12];        // 1600000
  const int F2 = in_sizes[10];        // 64
  const int KTOT = NBASIS * HID + HID;  // 640

  float* outp = (float*)d_out;                 // [N, F2]
  float* h0   = outp + (size_t)N * F2;         // [N, 128]
  float* h1   = h0 + (size_t)N * HID;          // [N, 128]

  char* ws = (char*)d_ws;
  size_t off = 0;
  auto alloc = [&](size_t bytes) -> void* {
    void* p = ws + off;
    off = (off + bytes + 255) & ~(size_t)255;
    return p;
  };
  int*    cnt      = (int*)alloc((size_t)N * NREL * 4);
  int*    rowptr   = (int*)alloc(((size_t)N + 1) * 4);
  int*    cursor   = (int*)alloc((size_t)N * 4);
  int*    csr      = (int*)alloc((size_t)E * 4);
  int*    blocksum = (int*)alloc(1024 * 4);
  int*    blockoff = (int*)alloc(1024 * 4);
  double* stats    = (double*)alloc(129 * 8);
  float*  mu       = (float*)alloc(128 * 4);
  float*  scale    = (float*)alloc(4);
  unsigned short* h0b = (unsigned short*)alloc((size_t)N * HID * 2);
  unsigned short* h1b = (unsigned short*)alloc((size_t)N * HID * 2);
  unsigned short* btPH = (unsigned short*)alloc((size_t)HID * HID * 2);
  unsigned short* btPL = (unsigned short*)alloc((size_t)HID * HID * 2);
  unsigned short* bt1H = (unsigned short*)alloc((size_t)HID * KTOT * 2);
  unsigned short* bt1L = (unsigned short*)alloc((size_t)HID * KTOT * 2);
  unsigned short* bt2H = (unsigned short*)alloc((size_t)F2 * KTOT * 2);
  unsigned short* bt2L = (unsigned short*)alloc((size_t)F2 * KTOT * 2);
  unsigned short* aggBb = (unsigned short*)(ws + off);
  size_t avail = (ws_size > off) ? ws_size - off : 0;
  size_t rowBytes = (size_t)(NBASIS * HID) * 2;  // bf16
  long chunk_rows = N;
  if (avail < (size_t)N * rowBytes) chunk_rows = (long)(avail / rowBytes);
  if (chunk_rows < 64) chunk_rows = 64;

  // 0. weight prep: transpose + bf16 hi/lo split (tiny)
  prep_kernel<<<(HID * HID + 255) / 256, 256, 0, stream>>>(W_proj, HID, W_proj, HID,
                                                           HID, btPH, btPL);
  prep_kernel<<<(KTOT * HID + 255) / 256, 256, 0, stream>>>(basis1, NBASIS * HID, root1,
                                                            KTOT, HID, bt1H, bt1L);
  prep_kernel<<<(KTOT * F2 + 255) / 256, 256, 0, stream>>>(basis2, NBASIS * HID, root2,
                                                           KTOT, F2, bt2H, bt2L);

  // 1. h0 = relu(x @ W_proj + b_proj); also write bf16 copy h0b
  mgemm_kernel<HID><<<(N + 63) / 64, 256, 0, stream>>>(
      nullptr, 0, xin, HID, btPH, btPL, b_proj, h0, h0b, N, 1);

  // 2. CSR build (shared by both layers)
  hipMemsetAsync(cnt, 0, (size_t)N * NREL * 4, stream);
  hist_kernel<<<2048, 256, 0, stream>>>(ei, et, cnt, E);
  int nb = (N + 255) / 256;
  scanA_kernel<<<nb, 256, 0, stream>>>(cnt, rowptr, blocksum, N);
  scanB_kernel<<<1, 1024, 0, stream>>>(blocksum, blockoff, nb);
  scanC_kernel<<<nb, 256, 0, stream>>>(rowptr, blockoff, cursor, N);
  scatter_kernel<<<2048, 256, 0, stream>>>(ei, et, cursor, csr, E, N);

  // 3. layer 1: RGCN -> relu (h1), then pairnorm in place (+ bf16 copy h1b)
  for (long r0 = 0; r0 < N; r0 += chunk_rows) {
    long rows = (N - r0 < chunk_rows) ? (N - r0) : chunk_rows;
    agg_kernel<<<(int)((rows + 3) / 4), 256, 0, stream>>>(h0b, rowptr, csr, cnt, comp1,
                                                          aggBb, (int)r0, (int)rows);
    mgemm_kernel<HID><<<(int)((rows + 63) / 64), 256, 0, stream>>>(
        aggBb, NBASIS * HID, h0 + r0 * HID, HID, bt1H, bt1L, bias1, h1 + r0 * HID,
        nullptr, (int)rows, 1);
  }
  hipMemsetAsync(stats, 0, 129 * 8, stream);
  stats_kernel<<<512, 256, 0, stream>>>(h1, N, HID, 7, stats, stats + 128);
  finalize_kernel<<<1, 128, 0, stream>>>(stats, stats + 128, N, HID, mu, scale);
  apply_kernel<<<2048, 256, 0, stream>>>(h1, mu, scale, N * HID / 4, HID, (uint2*)h1b);

  // 4. layer 2: RGCN (out), then pairnorm in place
  for (long r0 = 0; r0 < N; r0 += chunk_rows) {
    long rows = (N - r0 < chunk_rows) ? (N - r0) : chunk_rows;
    agg_kernel<<<(int)((rows + 3) / 4), 256, 0, stream>>>(h1b, rowptr, csr, cnt, comp2,
                                                          aggBb, (int)r0, (int)rows);
    mgemm_kernel<64><<<(int)((rows + 63) / 64), 256, 0, stream>>>(
        aggBb, NBASIS * HID, h1 + r0 * HID, HID, bt2H, bt2L, bias2, outp + r0 * F2,
        nullptr, (int)rows, 0);
  }
  hipMemsetAsync(stats, 0, 129 * 8, stream);
  stats_kernel<<<512, 256, 0, stream>>>(outp, N, F2, 6, stats, stats + 128);
  finalize_kernel<<<1, 128, 0, stream>>>(stats, stats + 128, N, F2, mu, scale);
  apply_kernel<<<2048, 256, 0, stream>>>(outp, mu, scale, N * F2 / 4, F2, nullptr);
}